// Round 4
// baseline (297.496 us; speedup 1.0000x reference)
//
#include <hip/hip_runtime.h>

// Problem constants (B=64, N=1024, D=128, K=6)
#define CB 64
#define CN 1024
#define CD 128
#define CK 6

typedef __attribute__((ext_vector_type(8))) short short8;
typedef __attribute__((ext_vector_type(4))) float floatx4;

__device__ __forceinline__ unsigned short f2bf(float f) {
    union { float f; unsigned u; } c; c.f = f;
    unsigned u = c.u;
    u += 0x7FFFu + ((u >> 16) & 1u);   // round-to-nearest-even
    return (unsigned short)(u >> 16);
}

// ---------------------------------------------------------------------------
// Fused: per-block (64 rows of one batch) KNN -> gathered-F2 GEMM -> epilogue.
// No workspace, no atomics. Writes h rows 1..1024 of each batch (f32).
// ---------------------------------------------------------------------------
__global__ void __launch_bounds__(256) k_main(
    const float* __restrict__ loc,     // [64][1024][2] f32
    const float* __restrict__ dl,      // [64][1024] f32
    const float* __restrict__ W2d,     // [128][2] f32
    const float* __restrict__ b2d,     // [128] f32
    const float* __restrict__ Wnb,     // [128][768] f32
    const float* __restrict__ bnb,     // [128] f32
    const float* __restrict__ W3d,     // [128][3] f32
    const float* __restrict__ b3d,     // [128] f32
    float* __restrict__ outh)          // [64][1025][128] f32
{
    __shared__ float2 pts[CN];          // this batch's points (KNN)
    __shared__ float2 pts0[CN];         // batch-0 points (F2 recompute)
    __shared__ float2 w2s[CD];
    __shared__ float  b2s[CD];
    __shared__ int    nbrs_s[64][CK];
    __shared__ unsigned short As[64 * 32];   // 4 KB
    __shared__ unsigned short Bs[128 * 32];  // 8 KB

    int t = threadIdx.x;
    long rowbase = (long)blockIdx.x * 64;
    int bb = (int)(rowbase >> 10);

    const float2* lb  = (const float2*)(loc + (long)bb * CN * 2);
    const float2* lb0 = (const float2*)loc;
#pragma unroll
    for (int r = 0; r < 4; ++r) {
        int p = t + r * 256;
        pts[p]  = lb[p];
        pts0[p] = lb0[p];
    }
    if (t < CD) {
        w2s[t] = ((const float2*)W2d)[t];
        b2s[t] = b2d[t];
    }
    __syncthreads();

    // ---- Phase 1: KNN, one thread per row. Bit-matches np f32:
    // d = sqrt((xj-xi)^2 + (yj-yi)^2), stable top-6 (ties -> lower index).
    if (t < 64) {
        int qn = (int)((rowbase + t) & 1023);
        float xq = pts[qn].x, yq = pts[qn].y;
        float dk[CK]; int ik[CK];
#pragma unroll
        for (int s = 0; s < CK; ++s) { dk[s] = 1e30f; ik[s] = 0; }
        for (int j = 0; j < CN; ++j) {
            float dx = __fsub_rn(pts[j].x, xq);
            float dy = __fsub_rn(pts[j].y, yq);
            float d2 = __fadd_rn(__fmul_rn(dx, dx), __fmul_rn(dy, dy));
            float ds = __fsqrt_rn(d2);
            if (ds < dk[CK - 1]) {
                float dc = ds; int jc = j;
#pragma unroll
                for (int s = 0; s < CK; ++s) {
                    bool sw = dc < dk[s];
                    float od = dk[s]; int oi = ik[s];
                    dk[s] = sw ? dc : od;
                    ik[s] = sw ? jc : oi;
                    dc = sw ? od : dc;
                    jc = sw ? oi : jc;
                }
            }
        }
#pragma unroll
        for (int s = 0; s < CK; ++s) nbrs_s[t][s] = ik[s];
    }
    __syncthreads();

    // ---- Phase 2: GEMM. M-tile 64, N=128, K=768 (6 neighbors x 128 feats).
    int wave = t >> 6, lane = t & 63;
    int wm = wave & 1, wn = wave >> 1;
    int arow = t >> 2, aseg = t & 3;
    int koff = (lane >> 4) * 8;
    int mrow = lane & 15;

    floatx4 acc[2][4];
#pragma unroll
    for (int i = 0; i < 2; ++i)
#pragma unroll
        for (int j = 0; j < 4; ++j) acc[i][j] = (floatx4){0.f, 0.f, 0.f, 0.f};

    for (int c = 0; c < 24; ++c) {
        int kk = c >> 2;
        int inner = (c & 3) * 32;
        __syncthreads();
        // A-tile: recompute F2[0][nb][inner..inner+32) on the fly (f32->bf16)
        {
            int nb = nbrs_s[arow][kk];
            float lx = pts0[nb].x, ly = pts0[nb].y;
            unsigned short tmp[8];
            int d0 = inner + aseg * 8;
#pragma unroll
            for (int e = 0; e < 8; ++e) {
                int d = d0 + e;
                tmp[e] = f2bf(lx * w2s[d].x + ly * w2s[d].y + b2s[d]);
            }
            *(uint4*)(&As[arow * 32 + aseg * 8]) = *(const uint4*)tmp;
        }
        // B-tile: load Wnb f32, convert to bf16
        {
            int dd = t >> 1, half = t & 1;
            const float4* src = (const float4*)(Wnb + dd * 768 + c * 32 + half * 16);
            float4 f0 = src[0], f1 = src[1], f2v = src[2], f3v = src[3];
            unsigned short tb[16];
            tb[0] = f2bf(f0.x);  tb[1] = f2bf(f0.y);  tb[2] = f2bf(f0.z);  tb[3] = f2bf(f0.w);
            tb[4] = f2bf(f1.x);  tb[5] = f2bf(f1.y);  tb[6] = f2bf(f1.z);  tb[7] = f2bf(f1.w);
            tb[8] = f2bf(f2v.x); tb[9] = f2bf(f2v.y); tb[10] = f2bf(f2v.z); tb[11] = f2bf(f2v.w);
            tb[12] = f2bf(f3v.x); tb[13] = f2bf(f3v.y); tb[14] = f2bf(f3v.z); tb[15] = f2bf(f3v.w);
            *(uint4*)(&Bs[dd * 32 + half * 16])     = *(const uint4*)tb;
            *(uint4*)(&Bs[dd * 32 + half * 16 + 8]) = *(const uint4*)(tb + 8);
        }
        __syncthreads();
        short8 af[2], bfr[4];
#pragma unroll
        for (int i = 0; i < 2; ++i)
            af[i] = *(const short8*)(&As[(wm * 32 + i * 16 + mrow) * 32 + koff]);
#pragma unroll
        for (int j = 0; j < 4; ++j)
            bfr[j] = *(const short8*)(&Bs[(wn * 64 + j * 16 + mrow) * 32 + koff]);
#pragma unroll
        for (int i = 0; i < 2; ++i)
#pragma unroll
            for (int j = 0; j < 4; ++j)
                acc[i][j] = __builtin_amdgcn_mfma_f32_16x16x32_bf16(
                    af[i], bfr[j], acc[i][j], 0, 0, 0);
    }

    // ---- Epilogue. C/D layout: col = lane&15, row = (lane>>4)*4 + reg.
    int lq = lane >> 4, lc = lane & 15;
    float rl0[8], rl1[8], rdl[8]; int rn[8];
#pragma unroll
    for (int ir = 0; ir < 8; ++ir) {
        int i = ir >> 2, r = ir & 3;
        long mg = rowbase + wm * 32 + i * 16 + lq * 4 + r;
        float2 l2 = ((const float2*)loc)[mg];
        rl0[ir] = l2.x;
        rl1[ir] = l2.y;
        rdl[ir] = dl[mg];
        rn[ir] = (int)(mg & 1023);
    }
#pragma unroll
    for (int j = 0; j < 4; ++j) {
        int d = wn * 64 + j * 16 + lc;
        float w0 = W3d[d * 3], w1 = W3d[d * 3 + 1], w2 = W3d[d * 3 + 2];
        float bias = b3d[d] + bnb[d];
#pragma unroll
        for (int ir = 0; ir < 8; ++ir) {
            int i = ir >> 2, r = ir & 3;
            float v = acc[i][j][r] + bias + rl0[ir] * w0 + rl1[ir] * w1 + rdl[ir] * w2;
            float lr = v >= 0.f ? v : 0.01f * v;
            outh[((long)bb * 1025 + rn[ir] + 1) * 128 + d] = lr;
        }
    }
}

// ---------------------------------------------------------------------------
// Depot row + mean (f32). One block per batch; re-reads the h rows k_main
// wrote (coalesced float4 loads), sums in f32, adds depot row, /1025.
// ---------------------------------------------------------------------------
__global__ void __launch_bounds__(256) k_final(
    const float* __restrict__ depot,
    const float* __restrict__ Wdep,
    const float* __restrict__ bdep,
    float* __restrict__ out)
{
    __shared__ float part[8][CD];    // 4 KB
    int t = threadIdx.x, b = blockIdx.x;
    const float* hb = out + (long)b * 1025 * 128;
    int rg = t >> 5;                 // row group 0..7
    int cq = t & 31;                 // col quad 0..31
    float4 s = make_float4(0.f, 0.f, 0.f, 0.f);
    for (int i = 0; i < 128; ++i) {
        const float4 v = *(const float4*)(hb + (long)(1 + i * 8 + rg) * 128 + cq * 4);
        s.x += v.x; s.y += v.y; s.z += v.z; s.w += v.w;
    }
    part[rg][cq * 4 + 0] = s.x;
    part[rg][cq * 4 + 1] = s.y;
    part[rg][cq * 4 + 2] = s.z;
    part[rg][cq * 4 + 3] = s.w;
    __syncthreads();
    if (t < CD) {
        float acc = 0.f;
#pragma unroll
        for (int g = 0; g < 8; ++g) acc += part[g][t];
        float dv = depot[b * 2] * Wdep[t * 2] + depot[b * 2 + 1] * Wdep[t * 2 + 1] + bdep[t];
        float lr = dv >= 0.f ? dv : 0.01f * dv;
        out[(long)b * 1025 * 128 + t] = lr;
        out[(long)CB * 1025 * 128 + b * 128 + t] = (acc + lr) * (1.0f / 1025.0f);
    }
}

extern "C" void kernel_launch(void* const* d_in, const int* in_sizes, int n_in,
                              void* d_out, int out_size, void* d_ws, size_t ws_size,
                              hipStream_t stream) {
    const float* loc      = (const float*)d_in[0];
    const float* deadline = (const float*)d_in[1];
    const float* depot    = (const float*)d_in[2];
    const float* W3d      = (const float*)d_in[3];
    const float* b3d      = (const float*)d_in[4];
    const float* W2d      = (const float*)d_in[5];
    const float* b2d      = (const float*)d_in[6];
    const float* Wnb      = (const float*)d_in[7];
    const float* bnb      = (const float*)d_in[8];
    const float* Wdep     = (const float*)d_in[9];
    const float* bdep     = (const float*)d_in[10];
    float* out = (float*)d_out;

    k_main<<<1024, 256, 0, stream>>>(loc, deadline, W2d, b2d, Wnb, bnb,
                                     W3d, b3d, out);
    k_final<<<64, 256, 0, stream>>>(depot, Wdep, bdep, out);
}

// Round 5
// 249.722 us; speedup vs baseline: 1.1913x; 1.1913x over previous
//
#include <hip/hip_runtime.h>
#include <hip/hip_bf16.h>

// Problem constants (B=64, N=1024, D=128, K=6)
#define CB 64
#define CN 1024
#define CD 128
#define CK 6

typedef __attribute__((ext_vector_type(8))) short short8;
typedef __attribute__((ext_vector_type(4))) float floatx4;

union BF2U { __hip_bfloat162 h2; unsigned u; };
__device__ __forceinline__ unsigned pack2bf(float a, float b) {
    BF2U c; c.h2 = __float22bfloat162_rn(make_float2(a, b)); return c.u;
}

// ---------------------------------------------------------------------------
// k_zero: zero the mean region of out (harness poisons d_out with 0xAA).
// ---------------------------------------------------------------------------
__global__ void k_zero(float* __restrict__ meanp) {
    meanp[blockIdx.x * 256 + threadIdx.x] = 0.f;
}

// ---------------------------------------------------------------------------
// Fused per-block (256 rows of one batch): KNN (1 query/thread) ->
// gathered-F2 bf16 MFMA GEMM -> fused F3/bias/leaky epilogue with
// column-sum atomics into the mean slot. Grid = 256 blocks (1/CU).
// ---------------------------------------------------------------------------
__global__ void __launch_bounds__(256, 1) k_main(
    const float* __restrict__ loc,     // [64][1024][2]
    const float* __restrict__ dl,      // [64][1024]
    const float* __restrict__ W2d,     // [128][2]
    const float* __restrict__ b2d,     // [128]
    const float* __restrict__ Wnb,     // [128][768]
    const float* __restrict__ bnb,     // [128]
    const float* __restrict__ W3d,     // [128][3]
    const float* __restrict__ b3d,     // [128]
    float* __restrict__ outh,          // [64][1025][128]
    float* __restrict__ meanp)         // [64][128] (pre-zeroed)
{
    __shared__ float2 pts[CN];               // this batch's points
    __shared__ float2 pts0[CN];              // batch-0 points (F2 recompute)
    __shared__ float2 w2s[CD];
    __shared__ float  b2s[CD];
    __shared__ int    nbrs_s[256][CK];       // 6 KB
    __shared__ unsigned short As[256 * 40];  // 20 KB, stride-40 pad (banks)
    __shared__ unsigned short Bs[128 * 32];  // 8 KB

    int t = threadIdx.x;
    int rowbase = blockIdx.x * 256;          // global row of tile start
    int bb = rowbase >> 10;                  // batch

    const float2* lb  = (const float2*)loc + bb * CN;
    const float2* lb0 = (const float2*)loc;
#pragma unroll
    for (int r = 0; r < 4; ++r) {
        int p = t + r * 256;
        pts[p]  = lb[p];
        pts0[p] = lb0[p];
    }
    if (t < CD) {
        w2s[t] = ((const float2*)W2d)[t];
        b2s[t] = b2d[t];
    }
    __syncthreads();

    // ---- Phase 1: KNN, one query per thread (all 256 active).
    // Bit-matches np f32: ds = sqrt_rn(add_rn(mul_rn(dx,dx),mul_rn(dy,dy))),
    // stable strict-< insertion (ties -> lower index), ascending j scan.
    {
        int qn = (rowbase + t) & 1023;
        float xq = pts[qn].x, yq = pts[qn].y;
        float dk[CK]; int ik[CK];
#pragma unroll
        for (int s = 0; s < CK; ++s) { dk[s] = 1e30f; ik[s] = 0; }
#define KNN_POINT(PX, PY, JJ)                                          \
        {                                                              \
            float dx = __fsub_rn(PX, xq);                              \
            float dy = __fsub_rn(PY, yq);                              \
            float d2 = __fadd_rn(__fmul_rn(dx, dx), __fmul_rn(dy, dy));\
            float ds = __fsqrt_rn(d2);                                 \
            if (ds < dk[CK - 1]) {                                     \
                float dc = ds; int jc = (JJ);                          \
                _Pragma("unroll")                                      \
                for (int s = 0; s < CK; ++s) {                         \
                    bool sw = dc < dk[s];                              \
                    float od = dk[s]; int oi = ik[s];                  \
                    dk[s] = sw ? dc : od;  ik[s] = sw ? jc : oi;       \
                    dc = sw ? od : dc;     jc = sw ? oi : jc;          \
                }                                                      \
            }                                                          \
        }
        for (int j = 0; j < CN; j += 4) {
            float2 p0 = pts[j], p1 = pts[j + 1], p2 = pts[j + 2], p3 = pts[j + 3];
            KNN_POINT(p0.x, p0.y, j)
            KNN_POINT(p1.x, p1.y, j + 1)
            KNN_POINT(p2.x, p2.y, j + 2)
            KNN_POINT(p3.x, p3.y, j + 3)
        }
#undef KNN_POINT
#pragma unroll
        for (int s = 0; s < CK; ++s) nbrs_s[t][s] = ik[s];
    }
    __syncthreads();

    // ---- Phase 2: GEMM. M-tile 256 (wave w -> rows w*64..w*64+63),
    // N = 128, K = 768 (6 neighbors x 128 feats), 24 chunks of 32.
    int wave = t >> 6, lane = t & 63;
    int koff = (lane >> 4) * 8;
    int mrow = lane & 15;

    floatx4 acc[4][8];
#pragma unroll
    for (int i = 0; i < 4; ++i)
#pragma unroll
        for (int j = 0; j < 8; ++j) acc[i][j] = (floatx4){0.f, 0.f, 0.f, 0.f};

    for (int c = 0; c < 24; ++c) {
        int kk = c >> 2;
        int inner = (c & 3) * 32;
        __syncthreads();
        // A-tile: thread t recomputes F2[0][nbr[t][kk]][inner..inner+32) bf16
        {
            int nb = nbrs_s[t][kk];
            float lx = pts0[nb].x, ly = pts0[nb].y;
            unsigned aw[16];
#pragma unroll
            for (int e = 0; e < 16; ++e) {
                int d = inner + e * 2;
                float v0 = fmaf(lx, w2s[d].x,     fmaf(ly, w2s[d].y,     b2s[d]));
                float v1 = fmaf(lx, w2s[d + 1].x, fmaf(ly, w2s[d + 1].y, b2s[d + 1]));
                aw[e] = pack2bf(v0, v1);
            }
            uint4* dst = (uint4*)&As[t * 40];
            dst[0] = make_uint4(aw[0], aw[1], aw[2], aw[3]);
            dst[1] = make_uint4(aw[4], aw[5], aw[6], aw[7]);
            dst[2] = make_uint4(aw[8], aw[9], aw[10], aw[11]);
            dst[3] = make_uint4(aw[12], aw[13], aw[14], aw[15]);
        }
        // B-tile: 128 rows (d) x 32, f32 -> bf16
        {
            int dd = t >> 1, half = t & 1;
            const float4* src = (const float4*)(Wnb + dd * 768 + c * 32 + half * 16);
            float4 f0 = src[0], f1 = src[1], f2v = src[2], f3v = src[3];
            uint4 w0 = make_uint4(pack2bf(f0.x, f0.y), pack2bf(f0.z, f0.w),
                                  pack2bf(f1.x, f1.y), pack2bf(f1.z, f1.w));
            uint4 w1 = make_uint4(pack2bf(f2v.x, f2v.y), pack2bf(f2v.z, f2v.w),
                                  pack2bf(f3v.x, f3v.y), pack2bf(f3v.z, f3v.w));
            *(uint4*)&Bs[dd * 32 + half * 16]     = w0;
            *(uint4*)&Bs[dd * 32 + half * 16 + 8] = w1;
        }
        __syncthreads();
        short8 af[4];
#pragma unroll
        for (int i = 0; i < 4; ++i)
            af[i] = *(const short8*)&As[(wave * 64 + i * 16 + mrow) * 40 + koff];
#pragma unroll
        for (int j = 0; j < 8; ++j) {
            short8 bfr = *(const short8*)&Bs[(j * 16 + mrow) * 32 + koff];
#pragma unroll
            for (int i = 0; i < 4; ++i)
                acc[i][j] = __builtin_amdgcn_mfma_f32_16x16x32_bf16(
                    af[i], bfr, acc[i][j], 0, 0, 0);
        }
    }

    // ---- Epilogue. C/D layout: col = lane&15, row = (lane>>4)*4 + reg.
    int lq = lane >> 4, lc = lane & 15;
    float rl0[16], rl1[16], rdl[16]; int rn[16];
#pragma unroll
    for (int ir = 0; ir < 16; ++ir) {
        int i = ir >> 2, r = ir & 3;
        int mg = rowbase + wave * 64 + i * 16 + lq * 4 + r;  // global row
        float2 l2 = ((const float2*)loc)[mg];
        rl0[ir] = l2.x;
        rl1[ir] = l2.y;
        rdl[ir] = dl[mg];
        rn[ir] = mg & 1023;
    }
#pragma unroll
    for (int j = 0; j < 8; ++j) {
        int d = j * 16 + lc;
        float w0 = W3d[d * 3], w1 = W3d[d * 3 + 1], w2 = W3d[d * 3 + 2];
        float bias = b3d[d] + bnb[d];
        float csum = 0.f;
#pragma unroll
        for (int ir = 0; ir < 16; ++ir) {
            int i = ir >> 2, r = ir & 3;
            float v = acc[i][j][r] + bias + rl0[ir] * w0 + rl1[ir] * w1 + rdl[ir] * w2;
            float lr = v >= 0.f ? v : 0.01f * v;
            outh[((long)bb * 1025 + rn[ir] + 1) * 128 + d] = lr;
            csum += lr;
        }
        csum += __shfl_xor(csum, 16);
        csum += __shfl_xor(csum, 32);
        if (lq == 0) atomicAdd(&meanp[bb * 128 + d], csum);
    }
}

// ---------------------------------------------------------------------------
// k_fin: depot row + mean finalize: mean = (colsum + depot_lr) / 1025.
// ---------------------------------------------------------------------------
__global__ void k_fin(const float* __restrict__ depot,
                      const float* __restrict__ Wdep,
                      const float* __restrict__ bdep,
                      float* __restrict__ out) {
    int idx = blockIdx.x * 256 + threadIdx.x;   // 64*128
    int b = idx >> 7, d = idx & 127;
    float dv = depot[b * 2] * Wdep[d * 2] + depot[b * 2 + 1] * Wdep[d * 2 + 1] + bdep[d];
    float lr = dv >= 0.f ? dv : 0.01f * dv;
    out[(long)b * 1025 * 128 + d] = lr;
    float* meanp = out + (long)CB * 1025 * 128;
    meanp[idx] = (meanp[idx] + lr) * (1.0f / 1025.0f);
}

extern "C" void kernel_launch(void* const* d_in, const int* in_sizes, int n_in,
                              void* d_out, int out_size, void* d_ws, size_t ws_size,
                              hipStream_t stream) {
    const float* loc      = (const float*)d_in[0];
    const float* deadline = (const float*)d_in[1];
    const float* depot    = (const float*)d_in[2];
    const float* W3d      = (const float*)d_in[3];
    const float* b3d      = (const float*)d_in[4];
    const float* W2d      = (const float*)d_in[5];
    const float* b2d      = (const float*)d_in[6];
    const float* Wnb      = (const float*)d_in[7];
    const float* bnb      = (const float*)d_in[8];
    const float* Wdep     = (const float*)d_in[9];
    const float* bdep     = (const float*)d_in[10];
    float* out = (float*)d_out;
    float* meanp = out + (long)CB * 1025 * 128;

    k_zero<<<32, 256, 0, stream>>>(meanp);
    k_main<<<256, 256, 0, stream>>>(loc, deadline, W2d, b2d, Wnb, bnb,
                                    W3d, b3d, out, meanp);
    k_fin<<<32, 256, 0, stream>>>(depot, Wdep, bdep, out);
}

// Round 6
// 198.430 us; speedup vs baseline: 1.4992x; 1.2585x over previous
//
#include <hip/hip_runtime.h>
#include <hip/hip_bf16.h>

// Problem constants (B=64, N=1024, D=128, K=6)
#define CB 64
#define CN 1024
#define CD 128
#define CK 6

typedef __attribute__((ext_vector_type(8))) short short8;
typedef __attribute__((ext_vector_type(4))) float floatx4;

union BF2U { __hip_bfloat162 h2; unsigned u; };
__device__ __forceinline__ unsigned pack2bf(float a, float b) {
    BF2U c; c.h2 = __float22bfloat162_rn(make_float2(a, b)); return c.u;
}
__device__ __forceinline__ unsigned short f2bf(float f) {
    union { float f; unsigned u; } c; c.f = f;
    unsigned u = c.u;
    u += 0x7FFFu + ((u >> 16) & 1u);
    return (unsigned short)(u >> 16);
}

// ws layout
#define WS_F2B   0          // [1024][128] bf16  = 256 KB
#define WS_WNBB  262144     // [128][768] bf16   = 192 KB
#define WS_PART  458752     // [1024][128] f32   = 512 KB  (per-block col partials)

// ---------------------------------------------------------------------------
// k_pre: F2 (batch 0) f32->bf16 and Wnb f32->bf16 into workspace.
// grid 512 x 256.
// ---------------------------------------------------------------------------
__global__ void k_pre(const float* __restrict__ loc,
                      const float* __restrict__ W2d,
                      const float* __restrict__ b2d,
                      const float* __restrict__ Wnb,
                      unsigned short* __restrict__ F2b,
                      unsigned short* __restrict__ Wnbb) {
    int idx = blockIdx.x * 256 + threadIdx.x;       // 0..131071
    int n = idx >> 7, d = idx & 127;
    float v = fmaf(loc[n * 2], W2d[d * 2], fmaf(loc[n * 2 + 1], W2d[d * 2 + 1], b2d[d]));
    F2b[idx] = f2bf(v);
    if (idx < 98304) Wnbb[idx] = f2bf(Wnb[idx]);
}

// ---------------------------------------------------------------------------
// k_main: per block = 64 rows of one batch.
//  Phase 1: KNN, 4 threads/query (256 pts each) + lexicographic merge.
//  Phase 2: 64x128 MFMA GEMM over gathered F2b rows, K=768.
//  Epilogue: F3 + bias + leaky, store h, per-block column partial sums to ws.
// ---------------------------------------------------------------------------
__global__ void __launch_bounds__(256) k_main(
    const float* __restrict__ loc,     // [64][1024][2]
    const float* __restrict__ dl,      // [64][1024]
    const unsigned short* __restrict__ F2b,   // [1024][128] bf16
    const unsigned short* __restrict__ Wnbb,  // [128][768] bf16
    const float* __restrict__ bnb,     // [128]
    const float* __restrict__ W3d,     // [128][3]
    const float* __restrict__ b3d,     // [128]
    float* __restrict__ outh,          // [64][1025][128]
    float* __restrict__ partials)      // [1024][128]
{
    __shared__ float2 pts[CN];               // 8 KB
    __shared__ float  mds[256][CK];          // 6 KB  partial dists
    __shared__ unsigned short midx[256][CK]; // 3 KB  partial indices
    __shared__ int    nbrs_s[64][CK];        // 1.5 KB
    __shared__ unsigned short As[64 * 40];   // 5 KB (stride-40 pad)
    __shared__ unsigned short Bs[128 * 40];  // 10 KB (stride-40 pad)
    __shared__ float  psum[4][CD];           // 2 KB

    int t = threadIdx.x;
    int rowbase = blockIdx.x * 64;
    int bb = rowbase >> 10;

    const float2* lb = (const float2*)loc + bb * CN;
#pragma unroll
    for (int r = 0; r < 4; ++r) pts[t + r * 256] = lb[t + r * 256];
    __syncthreads();

    // ---- Phase 1: KNN. seg = t>>6 scans points [seg*256, seg*256+256).
    {
        int q = t & 63, seg = t >> 6;
        int qn = (rowbase & 1023) + q;
        float xq = pts[qn].x, yq = pts[qn].y;
        float dk[CK]; int ik[CK];
#pragma unroll
        for (int s = 0; s < CK; ++s) { dk[s] = 1e30f; ik[s] = 0x7FFFFFFF; }
        float dk5sq = __builtin_inff();
        int j0 = seg * 256;
#define KNN_POINT(PX, PY, JJ)                                              \
        {                                                                  \
            float dx = __fsub_rn(PX, xq);                                  \
            float dy = __fsub_rn(PY, yq);                                  \
            float d2 = __fadd_rn(__fmul_rn(dx, dx), __fmul_rn(dy, dy));    \
            if (d2 < dk5sq) {                                              \
                float ds = __fsqrt_rn(d2);                                 \
                if (ds < dk[CK - 1]) {                                     \
                    float dc = ds; int jc = (JJ);                          \
                    _Pragma("unroll")                                      \
                    for (int s = 0; s < CK; ++s) {                         \
                        bool sw = dc < dk[s];                              \
                        float od = dk[s]; int oi = ik[s];                  \
                        dk[s] = sw ? dc : od;  ik[s] = sw ? jc : oi;       \
                        dc = sw ? od : dc;     jc = sw ? oi : jc;          \
                    }                                                      \
                    dk5sq = __fmul_rn(dk[CK-1], dk[CK-1]) * 1.000001f;     \
                }                                                          \
            }                                                              \
        }
        for (int j = 0; j < 256; j += 4) {
            float2 p0 = pts[j0 + j],     p1 = pts[j0 + j + 1];
            float2 p2 = pts[j0 + j + 2], p3 = pts[j0 + j + 3];
            KNN_POINT(p0.x, p0.y, j0 + j)
            KNN_POINT(p1.x, p1.y, j0 + j + 1)
            KNN_POINT(p2.x, p2.y, j0 + j + 2)
            KNN_POINT(p3.x, p3.y, j0 + j + 3)
        }
#undef KNN_POINT
#pragma unroll
        for (int s = 0; s < CK; ++s) {
            mds[t][s] = dk[s];
            midx[t][s] = (unsigned short)(ik[s] & 0xFFFF);
        }
    }
    __syncthreads();
    // merge 4 sorted lists per query (threads 0..63), ties -> lower index
    if (t < 64) {
        int p0 = 0, p1 = 0, p2 = 0, p3 = 0;
#pragma unroll
        for (int c = 0; c < CK; ++c) {
            float d0 = mds[t][p0],        d1 = mds[t + 64][p1];
            float d2v = mds[t + 128][p2], d3 = mds[t + 192][p3];
            int   i0 = midx[t][p0],       i1 = midx[t + 64][p1] ;
            int   i2 = midx[t + 128][p2], i3 = midx[t + 192][p3];
            // lexicographic min of (d, idx); segment order breaks d-ties
            float bd01 = (d1 < d0) ? d1 : d0;  int bi01 = (d1 < d0) ? i1 : i0;
            int   bg01 = (d1 < d0) ? 1 : 0;
            float bd23 = (d3 < d2v) ? d3 : d2v; int bi23 = (d3 < d2v) ? i3 : i2;
            int   bg23 = (d3 < d2v) ? 3 : 2;
            bool sel23 = (bd23 < bd01);
            int bi = sel23 ? bi23 : bi01;
            int bg = sel23 ? bg23 : bg01;
            nbrs_s[t][c] = bi;
            p0 += (bg == 0); p1 += (bg == 1); p2 += (bg == 2); p3 += (bg == 3);
        }
    }
    __syncthreads();

    // ---- Phase 2: GEMM. M=64 (wave w -> rows w*16..w*16+15), N=128, K=768.
    int wave = t >> 6, lane = t & 63;
    int koff = (lane >> 4) * 8;
    int mrow = lane & 15;
    int arow = t >> 2, aseg = t & 3;
    int bd = t >> 1, bhalf = t & 1;

    floatx4 acc[8];
#pragma unroll
    for (int j = 0; j < 8; ++j) acc[j] = (floatx4){0.f, 0.f, 0.f, 0.f};

    for (int c = 0; c < 24; ++c) {
        int kk = c >> 2;
        int inner = (c & 3) * 32;
        __syncthreads();
        // A: 64 rows x 32 bf16 gathered from F2b (L2-resident)
        {
            int nb = nbrs_s[arow][kk];
            *(uint4*)&As[arow * 40 + aseg * 8] =
                *(const uint4*)(F2b + nb * 128 + inner + aseg * 8);
        }
        // B: 128 rows x 32 bf16 from Wnbb
        {
            const uint4* src = (const uint4*)(Wnbb + bd * 768 + c * 32 + bhalf * 16);
            *(uint4*)&Bs[bd * 40 + bhalf * 16] = src[0];
            *(uint4*)&Bs[bd * 40 + bhalf * 16 + 8] = src[1];
        }
        __syncthreads();
        short8 af = *(const short8*)&As[(wave * 16 + mrow) * 40 + koff];
#pragma unroll
        for (int j = 0; j < 8; ++j) {
            short8 bfr = *(const short8*)&Bs[(j * 16 + mrow) * 40 + koff];
            acc[j] = __builtin_amdgcn_mfma_f32_16x16x32_bf16(af, bfr, acc[j], 0, 0, 0);
        }
    }

    // ---- Epilogue. C/D: col = lane&15, row = (lane>>4)*4 + reg.
    int lq = lane >> 4, lc = lane & 15;
    float rl0[4], rl1[4], rdl[4]; int rn[4];
#pragma unroll
    for (int r = 0; r < 4; ++r) {
        int mg = rowbase + wave * 16 + lq * 4 + r;
        float2 l2 = ((const float2*)loc)[mg];
        rl0[r] = l2.x; rl1[r] = l2.y; rdl[r] = dl[mg];
        rn[r] = mg & 1023;
    }
#pragma unroll
    for (int j = 0; j < 8; ++j) {
        int d = j * 16 + lc;
        float w0 = W3d[d * 3], w1 = W3d[d * 3 + 1], w2 = W3d[d * 3 + 2];
        float bias = b3d[d] + bnb[d];
        float csum = 0.f;
#pragma unroll
        for (int r = 0; r < 4; ++r) {
            float v = acc[j][r] + bias + rl0[r] * w0 + rl1[r] * w1 + rdl[r] * w2;
            float lr = v >= 0.f ? v : 0.01f * v;
            outh[((long)bb * 1025 + rn[r] + 1) * 128 + d] = lr;
            csum += lr;
        }
        csum += __shfl_xor(csum, 16);
        csum += __shfl_xor(csum, 32);
        if (lq == 0) psum[wave][d] = csum;
    }
    __syncthreads();
    if (t < CD)
        partials[blockIdx.x * 128 + t] =
            psum[0][t] + psum[1][t] + psum[2][t] + psum[3][t];
}

// ---------------------------------------------------------------------------
// k_fin: reduce 16 block-partials/batch + depot row + mean/1025.
// ---------------------------------------------------------------------------
__global__ void k_fin(const float* __restrict__ depot,
                      const float* __restrict__ Wdep,
                      const float* __restrict__ bdep,
                      const float* __restrict__ partials,
                      float* __restrict__ out) {
    int idx = blockIdx.x * 256 + threadIdx.x;   // 64*128
    int b = idx >> 7, d = idx & 127;
    float acc = 0.f;
#pragma unroll
    for (int g = 0; g < 16; ++g) acc += partials[(b * 16 + g) * 128 + d];
    float dv = depot[b * 2] * Wdep[d * 2] + depot[b * 2 + 1] * Wdep[d * 2 + 1] + bdep[d];
    float lr = dv >= 0.f ? dv : 0.01f * dv;
    out[(long)b * 1025 * 128 + d] = lr;
    out[(long)CB * 1025 * 128 + idx] = (acc + lr) * (1.0f / 1025.0f);
}

extern "C" void kernel_launch(void* const* d_in, const int* in_sizes, int n_in,
                              void* d_out, int out_size, void* d_ws, size_t ws_size,
                              hipStream_t stream) {
    const float* loc      = (const float*)d_in[0];
    const float* deadline = (const float*)d_in[1];
    const float* depot    = (const float*)d_in[2];
    const float* W3d      = (const float*)d_in[3];
    const float* b3d      = (const float*)d_in[4];
    const float* W2d      = (const float*)d_in[5];
    const float* b2d      = (const float*)d_in[6];
    const float* Wnb      = (const float*)d_in[7];
    const float* bnb      = (const float*)d_in[8];
    const float* Wdep     = (const float*)d_in[9];
    const float* bdep     = (const float*)d_in[10];
    float* out = (float*)d_out;

    char* ws = (char*)d_ws;
    unsigned short* F2b  = (unsigned short*)(ws + WS_F2B);
    unsigned short* Wnbb = (unsigned short*)(ws + WS_WNBB);
    float* partials      = (float*)(ws + WS_PART);

    k_pre<<<512, 256, 0, stream>>>(loc, W2d, b2d, Wnb, F2b, Wnbb);
    k_main<<<1024, 256, 0, stream>>>(loc, deadline, F2b, Wnbb, bnb,
                                     W3d, b3d, out, partials);
    k_fin<<<32, 256, 0, stream>>>(depot, Wdep, bdep, partials, out);
}

// Round 7
// 172.375 us; speedup vs baseline: 1.7259x; 1.1512x over previous
//
#include <hip/hip_runtime.h>
#include <hip/hip_bf16.h>

// Problem constants (B=64, N=1024, D=128, K=6)
#define CB 64
#define CN 1024
#define CD 128
#define CK 6

typedef __attribute__((ext_vector_type(8))) short short8;
typedef __attribute__((ext_vector_type(4))) float floatx4;

__device__ __forceinline__ unsigned short f2bf(float f) {
    union { float f; unsigned u; } c; c.f = f;
    unsigned u = c.u;
    u += 0x7FFFu + ((u >> 16) & 1u);
    return (unsigned short)(u >> 16);
}

// ws layout (bytes) — total ~1.92 MB (<= evidenced-safe 2 MB)
#define WS_F2B    0          // [1024][128] bf16 = 256 KB
#define WS_WNBB   262144     // [128][768] bf16  = 192 KB
#define WS_PART   458752     // [1024][128] f32  = 512 KB
#define WS_NBRS   983040     // [65536][6] u16   = 768 KB
#define WS_IDS    1769472    // [64][1024] u16   = 128 KB
#define WS_STARTS 1900544    // [64][257] i32    = 64.25 KB

// ---------------------------------------------------------------------------
// k_grid: one block per batch. (a) counting-sort points into 16x16 cells
// (ids permutation + starts prefix), (b) fused precompute of F2b (batch-0
// F2 in bf16) and Wnbb (Wnb in bf16) slices owned by this block.
// ---------------------------------------------------------------------------
__global__ void __launch_bounds__(256) k_grid(
    const float* __restrict__ loc,
    const float* __restrict__ W2d,
    const float* __restrict__ b2d,
    const float* __restrict__ Wnb,
    unsigned short* __restrict__ ids,
    int* __restrict__ starts,
    unsigned short* __restrict__ F2b,
    unsigned short* __restrict__ Wnbb)
{
    __shared__ float2 pts[CN];
    __shared__ int cnt[256];
    __shared__ int base[256];
    int b = blockIdx.x, t = threadIdx.x;
    const float2* lb = (const float2*)loc + b * CN;
#pragma unroll
    for (int r = 0; r < 4; ++r) pts[t + r * 256] = lb[t + r * 256];
    cnt[t] = 0;
    __syncthreads();
    int mycell[4];
#pragma unroll
    for (int r = 0; r < 4; ++r) {
        float2 p = pts[t * 4 + r];
        int cx = (int)(p.x * 16.0f); cx = cx > 15 ? 15 : cx;
        int cy = (int)(p.y * 16.0f); cy = cy > 15 ? 15 : cy;
        mycell[r] = (cy << 4) + cx;
        atomicAdd(&cnt[mycell[r]], 1);
    }
    __syncthreads();
    // inclusive Hillis-Steele scan over 256 cells
    for (int off = 1; off < 256; off <<= 1) {
        int u = (t >= off) ? cnt[t - off] : 0;
        __syncthreads();
        cnt[t] += u;
        __syncthreads();
    }
    int excl = (t == 0) ? 0 : cnt[t - 1];
    base[t] = excl;
    starts[b * 257 + t] = excl;
    if (t == 255) starts[b * 257 + 256] = cnt[255];
    __syncthreads();
#pragma unroll
    for (int r = 0; r < 4; ++r) {
        int pos = atomicAdd(&base[mycell[r]], 1);
        ids[b * CN + pos] = (unsigned short)(t * 4 + r);
    }
    // ---- fused precompute (independent of grid state) ----
    // F2b: rows [b*16, b*16+16): 2048 elems
#pragma unroll
    for (int e = 0; e < 8; ++e) {
        int idx = b * 2048 + e * 256 + t;
        int n = idx >> 7, d = idx & 127;
        float v = fmaf(loc[n * 2], W2d[d * 2],
                  fmaf(loc[n * 2 + 1], W2d[d * 2 + 1], b2d[d]));
        F2b[idx] = f2bf(v);
    }
    // Wnbb: 1536 elems per block
#pragma unroll
    for (int e = 0; e < 6; ++e) {
        int idx = b * 1536 + e * 256 + t;
        Wnbb[idx] = f2bf(Wnb[idx]);
    }
}

// ---------------------------------------------------------------------------
// k_knn: 256 blocks (4/batch) x 256 threads, one query per thread.
// Exact grid-pruned 6-NN: ring expansion with certified stop
// (dk[5] < 0.999999 * dist-to-ring-boundary). Same rn d^2/sqrt as numpy;
// lexicographic (ds, idx) strict-< insertion == jax.lax.top_k stable order.
// ---------------------------------------------------------------------------
__global__ void __launch_bounds__(256) k_knn(
    const float* __restrict__ loc,
    const unsigned short* __restrict__ ids,
    const int* __restrict__ starts,
    unsigned short* __restrict__ nbrs)
{
    __shared__ float xs[CN], ys[CN];
    __shared__ unsigned short ids_s[CN];
    __shared__ int st_s[257];
    int t = threadIdx.x;
    int b = blockIdx.x >> 2;
    int qbase = (blockIdx.x & 3) << 8;
    const float2* lb = (const float2*)loc + b * CN;
#pragma unroll
    for (int r = 0; r < 4; ++r) {
        int p = t + r * 256;
        float2 v = lb[p];
        xs[p] = v.x; ys[p] = v.y;
        ids_s[p] = ids[b * CN + p];
    }
    st_s[t] = starts[b * 257 + t];
    if (t == 0) st_s[256] = starts[b * 257 + 256];
    __syncthreads();

    int q = qbase + t;
    float xq = xs[q], yq = ys[q];
    int cx = (int)(xq * 16.0f); cx = cx > 15 ? 15 : cx;
    int cy = (int)(yq * 16.0f); cy = cy > 15 ? 15 : cy;
    float dk[CK]; int ik[CK];
#pragma unroll
    for (int s = 0; s < CK; ++s) { dk[s] = 1e30f; ik[s] = 0x7FFFFFFF; }
    const float h = 0.0625f;
    for (int r = 0; r < 16; ++r) {
        int x0 = cx - r, x1 = cx + r, y0 = cy - r, y1 = cy + r;
        int yl = y0 < 0 ? 0 : y0, yh = y1 > 15 ? 15 : y1;
        int xl = x0 < 0 ? 0 : x0, xh = x1 > 15 ? 15 : x1;
        for (int yy = yl; yy <= yh; ++yy) {
            bool ey = (yy == y0) || (yy == y1);
            for (int xx = xl; xx <= xh; ++xx) {
                if (!ey && xx != x0 && xx != x1) continue;  // annulus only
                int c = (yy << 4) + xx;
                int pe = st_s[c + 1];
                for (int p = st_s[c]; p < pe; ++p) {
                    int j = ids_s[p];
                    float dx = __fsub_rn(xs[j], xq);
                    float dy = __fsub_rn(ys[j], yq);
                    float d2 = __fadd_rn(__fmul_rn(dx, dx), __fmul_rn(dy, dy));
                    float ds = __fsqrt_rn(d2);
                    if (ds < dk[CK - 1] || (ds == dk[CK - 1] && j < ik[CK - 1])) {
                        float dc = ds; int jc = j;
#pragma unroll
                        for (int s = 0; s < CK; ++s) {
                            bool sw = (dc < dk[s]) || (dc == dk[s] && jc < ik[s]);
                            float od = dk[s]; int oi = ik[s];
                            dk[s] = sw ? dc : od; ik[s] = sw ? jc : oi;
                            dc = sw ? od : dc;    jc = sw ? oi : jc;
                        }
                    }
                }
            }
        }
        if (x0 <= 0 && y0 <= 0 && x1 >= 15 && y1 >= 15) break;  // all scanned
        float mL = x0 > 0  ? __fsub_rn(xq, (float)x0 * h)       : 1e30f;
        float mR = x1 < 15 ? __fsub_rn((float)(x1 + 1) * h, xq) : 1e30f;
        float mB = y0 > 0  ? __fsub_rn(yq, (float)y0 * h)       : 1e30f;
        float mT = y1 < 15 ? __fsub_rn((float)(y1 + 1) * h, yq) : 1e30f;
        float bound = fminf(fminf(mL, mR), fminf(mB, mT)) * 0.999999f;
        if (ik[CK - 1] != 0x7FFFFFFF && dk[CK - 1] < bound) break;
    }
    unsigned short* o = nbrs + (unsigned)(b * CN + q) * CK;
#pragma unroll
    for (int s = 0; s < CK; ++s) o[s] = (unsigned short)ik[s];
}

// ---------------------------------------------------------------------------
// k_gemm: per block = 64 rows of one batch. 64x128 MFMA tile, K=768
// (6 gathered F2b rows x 128). Fused F3 + bias + leaky epilogue; per-block
// column partials to ws (no atomics).
// ---------------------------------------------------------------------------
__global__ void __launch_bounds__(256) k_gemm(
    const float* __restrict__ loc,
    const float* __restrict__ dl,
    const unsigned short* __restrict__ F2b,   // [1024][128] bf16
    const unsigned short* __restrict__ Wnbb,  // [128][768] bf16
    const unsigned short* __restrict__ nbrs,  // [65536][6] u16
    const float* __restrict__ bnb,
    const float* __restrict__ W3d,
    const float* __restrict__ b3d,
    float* __restrict__ outh,          // [64][1025][128]
    float* __restrict__ partials)      // [1024][128]
{
    __shared__ int nbr_s[64][CK];            // 1.5 KB
    __shared__ unsigned short As[64 * 40];   // 5 KB (stride-40 pad)
    __shared__ unsigned short Bs[128 * 40];  // 10 KB
    __shared__ float psum[4][CD];            // 2 KB

    int t = threadIdx.x;
    int rowbase = blockIdx.x * 64;
    int bb = rowbase >> 10;

    if (t < 64) {
        int mg = rowbase + t;
#pragma unroll
        for (int s = 0; s < CK; ++s) nbr_s[t][s] = (int)nbrs[mg * CK + s];
    }

    int wave = t >> 6, lane = t & 63;
    int koff = (lane >> 4) * 8;
    int mrow = lane & 15;
    int arow = t >> 2, aseg = t & 3;
    int bd = t >> 1, bhalf = t & 1;

    floatx4 acc[8];
#pragma unroll
    for (int j = 0; j < 8; ++j) acc[j] = (floatx4){0.f, 0.f, 0.f, 0.f};

    for (int c = 0; c < 24; ++c) {
        int kk = c >> 2;
        int inner = (c & 3) * 32;
        __syncthreads();
        {
            int nb = nbr_s[arow][kk];
            *(uint4*)&As[arow * 40 + aseg * 8] =
                *(const uint4*)(F2b + nb * 128 + inner + aseg * 8);
        }
        {
            const uint4* src = (const uint4*)(Wnbb + bd * 768 + c * 32 + bhalf * 16);
            *(uint4*)&Bs[bd * 40 + bhalf * 16] = src[0];
            *(uint4*)&Bs[bd * 40 + bhalf * 16 + 8] = src[1];
        }
        __syncthreads();
        short8 af = *(const short8*)&As[(wave * 16 + mrow) * 40 + koff];
#pragma unroll
        for (int j = 0; j < 8; ++j) {
            short8 bfr = *(const short8*)&Bs[(j * 16 + mrow) * 40 + koff];
            acc[j] = __builtin_amdgcn_mfma_f32_16x16x32_bf16(af, bfr, acc[j], 0, 0, 0);
        }
    }

    // Epilogue. C/D: col = lane&15, row = (lane>>4)*4 + reg.
    int lq = lane >> 4, lc = lane & 15;
    float rl0[4], rl1[4], rdl[4]; int rn[4];
#pragma unroll
    for (int r = 0; r < 4; ++r) {
        int mg = rowbase + wave * 16 + lq * 4 + r;
        float2 l2 = ((const float2*)loc)[mg];
        rl0[r] = l2.x; rl1[r] = l2.y; rdl[r] = dl[mg];
        rn[r] = mg & 1023;
    }
#pragma unroll
    for (int j = 0; j < 8; ++j) {
        int d = j * 16 + lc;
        float w0 = W3d[d * 3], w1 = W3d[d * 3 + 1], w2 = W3d[d * 3 + 2];
        float bias = b3d[d] + bnb[d];
        float csum = 0.f;
#pragma unroll
        for (int r = 0; r < 4; ++r) {
            float v = acc[j][r] + bias + rl0[r] * w0 + rl1[r] * w1 + rdl[r] * w2;
            float lr = v >= 0.f ? v : 0.01f * v;
            outh[((long)bb * 1025 + rn[r] + 1) * 128 + d] = lr;
            csum += lr;
        }
        csum += __shfl_xor(csum, 16);
        csum += __shfl_xor(csum, 32);
        if (lq == 0) psum[wave][d] = csum;
    }
    __syncthreads();
    if (t < CD)
        partials[blockIdx.x * 128 + t] =
            psum[0][t] + psum[1][t] + psum[2][t] + psum[3][t];
}

// ---------------------------------------------------------------------------
// k_fin: reduce 16 block-partials/batch + depot row + mean/1025.
// ---------------------------------------------------------------------------
__global__ void k_fin(const float* __restrict__ depot,
                      const float* __restrict__ Wdep,
                      const float* __restrict__ bdep,
                      const float* __restrict__ partials,
                      float* __restrict__ out) {
    int idx = blockIdx.x * 256 + threadIdx.x;   // 64*128
    int b = idx >> 7, d = idx & 127;
    float acc = 0.f;
#pragma unroll
    for (int g = 0; g < 16; ++g) acc += partials[(b * 16 + g) * 128 + d];
    float dv = depot[b * 2] * Wdep[d * 2] + depot[b * 2 + 1] * Wdep[d * 2 + 1] + bdep[d];
    float lr = dv >= 0.f ? dv : 0.01f * dv;
    out[(long)b * 1025 * 128 + d] = lr;
    out[(long)CB * 1025 * 128 + idx] = (acc + lr) * (1.0f / 1025.0f);
}

extern "C" void kernel_launch(void* const* d_in, const int* in_sizes, int n_in,
                              void* d_out, int out_size, void* d_ws, size_t ws_size,
                              hipStream_t stream) {
    const float* loc      = (const float*)d_in[0];
    const float* deadline = (const float*)d_in[1];
    const float* depot    = (const float*)d_in[2];
    const float* W3d      = (const float*)d_in[3];
    const float* b3d      = (const float*)d_in[4];
    const float* W2d      = (const float*)d_in[5];
    const float* b2d      = (const float*)d_in[6];
    const float* Wnb      = (const float*)d_in[7];
    const float* bnb      = (const float*)d_in[8];
    const float* Wdep     = (const float*)d_in[9];
    const float* bdep     = (const float*)d_in[10];
    float* out = (float*)d_out;

    char* ws = (char*)d_ws;
    unsigned short* F2b   = (unsigned short*)(ws + WS_F2B);
    unsigned short* Wnbb  = (unsigned short*)(ws + WS_WNBB);
    float* partials       = (float*)(ws + WS_PART);
    unsigned short* nbrs  = (unsigned short*)(ws + WS_NBRS);
    unsigned short* ids   = (unsigned short*)(ws + WS_IDS);
    int* starts           = (int*)(ws + WS_STARTS);

    k_grid<<<64, 256, 0, stream>>>(loc, W2d, b2d, Wnb, ids, starts, F2b, Wnbb);
    k_knn<<<256, 256, 0, stream>>>(loc, ids, starts, nbrs);
    k_gemm<<<1024, 256, 0, stream>>>(loc, deadline, F2b, Wnbb, nbrs, bnb,
                                     W3d, b3d, out, partials);
    k_fin<<<32, 256, 0, stream>>>(depot, Wdep, bdep, partials, out);
}

// Round 8
// 151.462 us; speedup vs baseline: 1.9642x; 1.1381x over previous
//
#include <hip/hip_runtime.h>
#include <hip/hip_bf16.h>

// Problem constants (B=64, N=1024, D=128, K=6)
#define CB 64
#define CN 1024
#define CD 128
#define CK 6

typedef __attribute__((ext_vector_type(8))) short short8;
typedef __attribute__((ext_vector_type(4))) float floatx4;

__device__ __forceinline__ unsigned short f2bf(float f) {
    union { float f; unsigned u; } c; c.f = f;
    unsigned u = c.u;
    u += 0x7FFFu + ((u >> 16) & 1u);
    return (unsigned short)(u >> 16);
}

// ws layout (bytes) — total ~1.92 MB
#define WS_F2B    0          // [1024][128] bf16 = 256 KB
#define WS_WNBB   262144     // [128][768] bf16  = 192 KB
#define WS_PART   458752     // [512][128] f32   = 256 KB (512 KB reserved)
#define WS_NBRS   983040     // [65536][6] u16   = 768 KB
#define WS_IDS    1769472    // [64][1024] u16   = 128 KB
#define WS_STARTS 1900544    // [64][257] i32    = 64.25 KB

// ---------------------------------------------------------------------------
// k_grid: one block per batch. (a) counting-sort points into 16x16 cells,
// (b) fused precompute of F2b (batch-0 F2, bf16) and Wnbb (bf16) slices.
// ---------------------------------------------------------------------------
__global__ void __launch_bounds__(256) k_grid(
    const float* __restrict__ loc,
    const float* __restrict__ W2d,
    const float* __restrict__ b2d,
    const float* __restrict__ Wnb,
    unsigned short* __restrict__ ids,
    int* __restrict__ starts,
    unsigned short* __restrict__ F2b,
    unsigned short* __restrict__ Wnbb)
{
    __shared__ float2 pts[CN];
    __shared__ int cnt[256];
    __shared__ int base[256];
    int b = blockIdx.x, t = threadIdx.x;
    const float2* lb = (const float2*)loc + b * CN;
#pragma unroll
    for (int r = 0; r < 4; ++r) pts[t + r * 256] = lb[t + r * 256];
    cnt[t] = 0;
    __syncthreads();
    int mycell[4];
#pragma unroll
    for (int r = 0; r < 4; ++r) {
        float2 p = pts[t * 4 + r];
        int cx = (int)(p.x * 16.0f); cx = cx > 15 ? 15 : cx;
        int cy = (int)(p.y * 16.0f); cy = cy > 15 ? 15 : cy;
        mycell[r] = (cy << 4) + cx;
        atomicAdd(&cnt[mycell[r]], 1);
    }
    __syncthreads();
    for (int off = 1; off < 256; off <<= 1) {
        int u = (t >= off) ? cnt[t - off] : 0;
        __syncthreads();
        cnt[t] += u;
        __syncthreads();
    }
    int excl = (t == 0) ? 0 : cnt[t - 1];
    base[t] = excl;
    starts[b * 257 + t] = excl;
    if (t == 255) starts[b * 257 + 256] = cnt[255];
    __syncthreads();
#pragma unroll
    for (int r = 0; r < 4; ++r) {
        int pos = atomicAdd(&base[mycell[r]], 1);
        ids[b * CN + pos] = (unsigned short)(t * 4 + r);
    }
    // fused precompute
#pragma unroll
    for (int e = 0; e < 8; ++e) {
        int idx = b * 2048 + e * 256 + t;
        int n = idx >> 7, d = idx & 127;
        float v = fmaf(loc[n * 2], W2d[d * 2],
                  fmaf(loc[n * 2 + 1], W2d[d * 2 + 1], b2d[d]));
        F2b[idx] = f2bf(v);
    }
#pragma unroll
    for (int e = 0; e < 6; ++e) {
        int idx = b * 1536 + e * 256 + t;
        Wnbb[idx] = f2bf(Wnb[idx]);
    }
}

// ---------------------------------------------------------------------------
// k_knn: 256 blocks (4/batch) x 256 threads. Thread t handles the query at
// SORTED position qbase+t (cell-coherent waves). Candidate coords read from
// sorted-order LDS arrays (independent loads). Exact ring expansion with
// certified stop; lexicographic (ds, idx) insertion == jax.lax.top_k order.
// ---------------------------------------------------------------------------
__global__ void __launch_bounds__(256) k_knn(
    const float* __restrict__ loc,
    const unsigned short* __restrict__ ids,
    const int* __restrict__ starts,
    unsigned short* __restrict__ nbrs)
{
    __shared__ float xs[CN], ys[CN];
    __shared__ float xsrt[CN], ysrt[CN];
    __shared__ unsigned short ids_s[CN];
    __shared__ int st_s[257];
    int t = threadIdx.x;
    int b = blockIdx.x >> 2;
    int qbase = (blockIdx.x & 3) << 8;
    const float2* lb = (const float2*)loc + b * CN;
#pragma unroll
    for (int r = 0; r < 4; ++r) {
        int p = t + r * 256;
        float2 v = lb[p];
        xs[p] = v.x; ys[p] = v.y;
        ids_s[p] = ids[b * CN + p];
    }
    st_s[t] = starts[b * 257 + t];
    if (t == 0) st_s[256] = starts[b * 257 + 256];
    __syncthreads();
#pragma unroll
    for (int r = 0; r < 4; ++r) {
        int p = t + r * 256;
        int j = ids_s[p];
        xsrt[p] = xs[j]; ysrt[p] = ys[j];
    }
    __syncthreads();

    int qp = qbase + t;
    int q = ids_s[qp];
    float xq = xsrt[qp], yq = ysrt[qp];
    int cx = (int)(xq * 16.0f); cx = cx > 15 ? 15 : cx;
    int cy = (int)(yq * 16.0f); cy = cy > 15 ? 15 : cy;
    float dk[CK]; int ik[CK];
#pragma unroll
    for (int s = 0; s < CK; ++s) { dk[s] = 1e30f; ik[s] = 0x7FFFFFFF; }
    float dk5sq = __builtin_inff();
    const float h = 0.0625f;
    for (int r = 0; r < 16; ++r) {
        int x0 = cx - r, x1 = cx + r, y0 = cy - r, y1 = cy + r;
        int yl = y0 < 0 ? 0 : y0, yh = y1 > 15 ? 15 : y1;
        int xl = x0 < 0 ? 0 : x0, xh = x1 > 15 ? 15 : x1;
        for (int yy = yl; yy <= yh; ++yy) {
            bool ey = (yy == y0) || (yy == y1);
            for (int xx = xl; xx <= xh; ++xx) {
                if (!ey && xx != x0 && xx != x1) continue;  // annulus only
                int c = (yy << 4) + xx;
                int pe = st_s[c + 1];
                for (int p = st_s[c]; p < pe; ++p) {
                    float dx = __fsub_rn(xsrt[p], xq);
                    float dy = __fsub_rn(ysrt[p], yq);
                    float d2 = __fadd_rn(__fmul_rn(dx, dx), __fmul_rn(dy, dy));
                    if (d2 < dk5sq) {
                        float ds = __fsqrt_rn(d2);
                        int j = ids_s[p];
                        if (ds < dk[CK - 1] || (ds == dk[CK - 1] && j < ik[CK - 1])) {
                            float dc = ds; int jc = j;
#pragma unroll
                            for (int s = 0; s < CK; ++s) {
                                bool sw = (dc < dk[s]) || (dc == dk[s] && jc < ik[s]);
                                float od = dk[s]; int oi = ik[s];
                                dk[s] = sw ? dc : od; ik[s] = sw ? jc : oi;
                                dc = sw ? od : dc;    jc = sw ? oi : jc;
                            }
                            dk5sq = __fmul_rn(dk[CK - 1], dk[CK - 1]) * 1.000001f;
                        }
                    }
                }
            }
        }
        if (x0 <= 0 && y0 <= 0 && x1 >= 15 && y1 >= 15) break;
        float mL = x0 > 0  ? __fsub_rn(xq, (float)x0 * h)       : 1e30f;
        float mR = x1 < 15 ? __fsub_rn((float)(x1 + 1) * h, xq) : 1e30f;
        float mB = y0 > 0  ? __fsub_rn(yq, (float)y0 * h)       : 1e30f;
        float mT = y1 < 15 ? __fsub_rn((float)(y1 + 1) * h, yq) : 1e30f;
        float bound = fminf(fminf(mL, mR), fminf(mB, mT)) * 0.999999f;
        if (ik[CK - 1] != 0x7FFFFFFF && dk[CK - 1] < bound) break;
    }
    unsigned short* o = nbrs + (unsigned)(b * CN + q) * CK;
#pragma unroll
    for (int s = 0; s < CK; ++s) o[s] = (unsigned short)ik[s];
}

// ---------------------------------------------------------------------------
// k_gemm: per block = 128 rows of one batch (512 blocks). Per-wave 32 rows,
// acc[2][8]. K=768 in 24 chunks of 32, fully unrolled, neighbor indices in
// registers. Fused F3 + bias + leaky epilogue; per-block column partials.
// ---------------------------------------------------------------------------
__global__ void __launch_bounds__(256) k_gemm(
    const float* __restrict__ loc,
    const float* __restrict__ dl,
    const unsigned short* __restrict__ F2b,   // [1024][128] bf16
    const unsigned short* __restrict__ Wnbb,  // [128][768] bf16
    const unsigned short* __restrict__ nbrs,  // [65536][6] u16
    const float* __restrict__ bnb,
    const float* __restrict__ W3d,
    const float* __restrict__ b3d,
    float* __restrict__ outh,          // [64][1025][128]
    float* __restrict__ partials)      // [512][128]
{
    __shared__ unsigned short As[128 * 40];  // 10 KB (stride-40 pad)
    __shared__ unsigned short Bs[128 * 40];  // 10 KB
    __shared__ float psum[4][CD];            // 2 KB

    int t = threadIdx.x;
    int rowbase = blockIdx.x * 128;
    int bb = rowbase >> 10;

    // staging rows owned by this thread: r0 = t>>2, r1 = r0+64
    int ar0 = t >> 2, aseg = t & 3;
    int nb0[CK], nb1[CK];
#pragma unroll
    for (int s = 0; s < CK; ++s) {
        nb0[s] = (int)nbrs[(rowbase + ar0) * CK + s];
        nb1[s] = (int)nbrs[(rowbase + ar0 + 64) * CK + s];
    }

    int wave = t >> 6, lane = t & 63;
    int koff = (lane >> 4) * 8;
    int mrow = lane & 15;
    int bd = t >> 1, bhalf = t & 1;

    floatx4 acc[2][8];
#pragma unroll
    for (int i = 0; i < 2; ++i)
#pragma unroll
        for (int j = 0; j < 8; ++j) acc[i][j] = (floatx4){0.f, 0.f, 0.f, 0.f};

#pragma unroll
    for (int c = 0; c < 24; ++c) {
        const int kk = c >> 2;
        const int inner = (c & 3) * 32;
        __syncthreads();
        *(uint4*)&As[ar0 * 40 + aseg * 8] =
            *(const uint4*)(F2b + nb0[kk] * 128 + inner + aseg * 8);
        *(uint4*)&As[(ar0 + 64) * 40 + aseg * 8] =
            *(const uint4*)(F2b + nb1[kk] * 128 + inner + aseg * 8);
        {
            const uint4* src = (const uint4*)(Wnbb + bd * 768 + c * 32 + bhalf * 16);
            *(uint4*)&Bs[bd * 40 + bhalf * 16] = src[0];
            *(uint4*)&Bs[bd * 40 + bhalf * 16 + 8] = src[1];
        }
        __syncthreads();
        short8 af[2];
#pragma unroll
        for (int i = 0; i < 2; ++i)
            af[i] = *(const short8*)&As[(wave * 32 + i * 16 + mrow) * 40 + koff];
#pragma unroll
        for (int j = 0; j < 8; ++j) {
            short8 bfr = *(const short8*)&Bs[(j * 16 + mrow) * 40 + koff];
#pragma unroll
            for (int i = 0; i < 2; ++i)
                acc[i][j] = __builtin_amdgcn_mfma_f32_16x16x32_bf16(
                    af[i], bfr, acc[i][j], 0, 0, 0);
        }
    }

    // Epilogue. C/D: col = lane&15, row = (lane>>4)*4 + reg.
    int lq = lane >> 4, lc = lane & 15;
    float rl0[8], rl1[8], rdl[8]; int rn[8];
#pragma unroll
    for (int ir = 0; ir < 8; ++ir) {
        int i = ir >> 2, r = ir & 3;
        int mg = rowbase + wave * 32 + i * 16 + lq * 4 + r;
        float2 l2 = ((const float2*)loc)[mg];
        rl0[ir] = l2.x; rl1[ir] = l2.y; rdl[ir] = dl[mg];
        rn[ir] = mg & 1023;
    }
#pragma unroll
    for (int j = 0; j < 8; ++j) {
        int d = j * 16 + lc;
        float w0 = W3d[d * 3], w1 = W3d[d * 3 + 1], w2 = W3d[d * 3 + 2];
        float bias = b3d[d] + bnb[d];
        float csum = 0.f;
#pragma unroll
        for (int ir = 0; ir < 8; ++ir) {
            int i = ir >> 2, r = ir & 3;
            float v = acc[i][j][r] + bias + rl0[ir] * w0 + rl1[ir] * w1 + rdl[ir] * w2;
            float lr = v >= 0.f ? v : 0.01f * v;
            outh[((long)bb * 1025 + rn[ir] + 1) * 128 + d] = lr;
            csum += lr;
        }
        csum += __shfl_xor(csum, 16);
        csum += __shfl_xor(csum, 32);
        if (lq == 0) psum[wave][d] = csum;
    }
    __syncthreads();
    if (t < CD)
        partials[blockIdx.x * 128 + t] =
            psum[0][t] + psum[1][t] + psum[2][t] + psum[3][t];
}

// ---------------------------------------------------------------------------
// k_fin: reduce 8 block-partials/batch + depot row + mean/1025.
// ---------------------------------------------------------------------------
__global__ void k_fin(const float* __restrict__ depot,
                      const float* __restrict__ Wdep,
                      const float* __restrict__ bdep,
                      const float* __restrict__ partials,
                      float* __restrict__ out) {
    int idx = blockIdx.x * 256 + threadIdx.x;   // 64*128
    int b = idx >> 7, d = idx & 127;
    float acc = 0.f;
#pragma unroll
    for (int g = 0; g < 8; ++g) acc += partials[(b * 8 + g) * 128 + d];
    float dv = depot[b * 2] * Wdep[d * 2] + depot[b * 2 + 1] * Wdep[d * 2 + 1] + bdep[d];
    float lr = dv >= 0.f ? dv : 0.01f * dv;
    out[(long)b * 1025 * 128 + d] = lr;
    out[(long)CB * 1025 * 128 + idx] = (acc + lr) * (1.0f / 1025.0f);
}

extern "C" void kernel_launch(void* const* d_in, const int* in_sizes, int n_in,
                              void* d_out, int out_size, void* d_ws, size_t ws_size,
                              hipStream_t stream) {
    const float* loc      = (const float*)d_in[0];
    const float* deadline = (const float*)d_in[1];
    const float* depot    = (const float*)d_in[2];
    const float* W3d      = (const float*)d_in[3];
    const float* b3d      = (const float*)d_in[4];
    const float* W2d      = (const float*)d_in[5];
    const float* b2d      = (const float*)d_in[6];
    const float* Wnb      = (const float*)d_in[7];
    const float* bnb      = (const float*)d_in[8];
    const float* Wdep     = (const float*)d_in[9];
    const float* bdep     = (const float*)d_in[10];
    float* out = (float*)d_out;

    char* ws = (char*)d_ws;
    unsigned short* F2b   = (unsigned short*)(ws + WS_F2B);
    unsigned short* Wnbb  = (unsigned short*)(ws + WS_WNBB);
    float* partials       = (float*)(ws + WS_PART);
    unsigned short* nbrs  = (unsigned short*)(ws + WS_NBRS);
    unsigned short* ids   = (unsigned short*)(ws + WS_IDS);
    int* starts           = (int*)(ws + WS_STARTS);

    k_grid<<<64, 256, 0, stream>>>(loc, W2d, b2d, Wnb, ids, starts, F2b, Wnbb);
    k_knn<<<256, 256, 0, stream>>>(loc, ids, starts, nbrs);
    k_gemm<<<512, 256, 0, stream>>>(loc, deadline, F2b, Wnbb, nbrs, bnb,
                                    W3d, b3d, out, partials);
    k_fin<<<32, 256, 0, stream>>>(depot, Wdep, bdep, partials, out);
}

// Round 9
// 142.915 us; speedup vs baseline: 2.0816x; 1.0598x over previous
//
#include <hip/hip_runtime.h>
#include <hip/hip_bf16.h>

// Problem constants (B=64, N=1024, D=128, K=6)
#define CB 64
#define CN 1024
#define CD 128
#define CK 6

typedef __attribute__((ext_vector_type(8))) short short8;
typedef __attribute__((ext_vector_type(4))) float floatx4;

__device__ __forceinline__ unsigned short f2bf(float f) {
    union { float f; unsigned u; } c; c.f = f;
    unsigned u = c.u;
    u += 0x7FFFu + ((u >> 16) & 1u);
    return (unsigned short)(u >> 16);
}

// ws layout (bytes) — total ~1.92 MB
#define WS_F2B    0          // [1024][128] bf16 = 256 KB
#define WS_WNBB   262144     // [128][768] bf16  = 192 KB
#define WS_PART   458752     // [512][128] f32   = 256 KB (512 KB reserved)
#define WS_NBRS   983040     // [65536][6] u16   = 768 KB
#define WS_IDS    1769472    // [64][1024] u16   = 128 KB
#define WS_STARTS 1900544    // [64][257] i32    = 64.25 KB

// ---------------------------------------------------------------------------
// k_grid: one block per batch. (a) counting-sort points into 16x16 cells,
// (b) fused precompute of F2b (batch-0 F2, bf16) and Wnbb (bf16) slices.
// ---------------------------------------------------------------------------
__global__ void __launch_bounds__(256) k_grid(
    const float* __restrict__ loc,
    const float* __restrict__ W2d,
    const float* __restrict__ b2d,
    const float* __restrict__ Wnb,
    unsigned short* __restrict__ ids,
    int* __restrict__ starts,
    unsigned short* __restrict__ F2b,
    unsigned short* __restrict__ Wnbb)
{
    __shared__ float2 pts[CN];
    __shared__ int cnt[256];
    __shared__ int base[256];
    int b = blockIdx.x, t = threadIdx.x;
    const float2* lb = (const float2*)loc + b * CN;
#pragma unroll
    for (int r = 0; r < 4; ++r) pts[t + r * 256] = lb[t + r * 256];
    cnt[t] = 0;
    __syncthreads();
    int mycell[4];
#pragma unroll
    for (int r = 0; r < 4; ++r) {
        float2 p = pts[t * 4 + r];
        int cx = (int)(p.x * 16.0f); cx = cx > 15 ? 15 : cx;
        int cy = (int)(p.y * 16.0f); cy = cy > 15 ? 15 : cy;
        mycell[r] = (cy << 4) + cx;
        atomicAdd(&cnt[mycell[r]], 1);
    }
    __syncthreads();
    for (int off = 1; off < 256; off <<= 1) {
        int u = (t >= off) ? cnt[t - off] : 0;
        __syncthreads();
        cnt[t] += u;
        __syncthreads();
    }
    int excl = (t == 0) ? 0 : cnt[t - 1];
    base[t] = excl;
    starts[b * 257 + t] = excl;
    if (t == 255) starts[b * 257 + 256] = cnt[255];
    __syncthreads();
#pragma unroll
    for (int r = 0; r < 4; ++r) {
        int pos = atomicAdd(&base[mycell[r]], 1);
        ids[b * CN + pos] = (unsigned short)(t * 4 + r);
    }
    // fused precompute
#pragma unroll
    for (int e = 0; e < 8; ++e) {
        int idx = b * 2048 + e * 256 + t;
        int n = idx >> 7, d = idx & 127;
        float v = fmaf(loc[n * 2], W2d[d * 2],
                  fmaf(loc[n * 2 + 1], W2d[d * 2 + 1], b2d[d]));
        F2b[idx] = f2bf(v);
    }
#pragma unroll
    for (int e = 0; e < 6; ++e) {
        int idx = b * 1536 + e * 256 + t;
        Wnbb[idx] = f2bf(Wnb[idx]);
    }
}

// ---------------------------------------------------------------------------
// k_knn: 256 blocks (4/batch) x 256 threads, one query per thread (query at
// SORTED position qbase+t -> cell-coherent waves). Fast path: the 3x3 cell
// neighborhood is 3 CONTIGUOUS sorted ranges (cells cx-1..cx+1 at one cy are
// consecutive cell ids) -> 3 tight loops over xy-interleaved LDS. Certified
// r=1 bound check; rare failures fall into the general ring loop (r>=2).
// Lexicographic (ds, idx) insertion == jax.lax.top_k stable order.
// ---------------------------------------------------------------------------
__global__ void __launch_bounds__(256) k_knn(
    const float* __restrict__ loc,
    const unsigned short* __restrict__ ids,
    const int* __restrict__ starts,
    unsigned short* __restrict__ nbrs)
{
    __shared__ float2 xy_tmp[CN];            // original order
    __shared__ float2 xy_s[CN];              // sorted order
    __shared__ unsigned short ids_s[CN];
    __shared__ int st_s[257];
    int t = threadIdx.x;
    int b = blockIdx.x >> 2;
    int qbase = (blockIdx.x & 3) << 8;
    const float2* lb = (const float2*)loc + b * CN;
#pragma unroll
    for (int r = 0; r < 4; ++r) {
        int p = t + r * 256;
        xy_tmp[p] = lb[p];
        ids_s[p] = ids[b * CN + p];
    }
    st_s[t] = starts[b * 257 + t];
    if (t == 0) st_s[256] = starts[b * 257 + 256];
    __syncthreads();
#pragma unroll
    for (int r = 0; r < 4; ++r) {
        int p = t + r * 256;
        xy_s[p] = xy_tmp[ids_s[p]];
    }
    __syncthreads();

    int qp = qbase + t;
    int q = ids_s[qp];
    float2 qxy = xy_s[qp];
    float xq = qxy.x, yq = qxy.y;
    int cx = (int)(xq * 16.0f); cx = cx > 15 ? 15 : cx;
    int cy = (int)(yq * 16.0f); cy = cy > 15 ? 15 : cy;
    float dk[CK]; int ik[CK];
#pragma unroll
    for (int s = 0; s < CK; ++s) { dk[s] = 1e30f; ik[s] = 0x7FFFFFFF; }
    float dk5sq = __builtin_inff();
    const float h = 0.0625f;

#define KNN_CAND(P)                                                        \
    {                                                                      \
        float2 v = xy_s[P];                                                \
        float dx = __fsub_rn(v.x, xq);                                     \
        float dy = __fsub_rn(v.y, yq);                                     \
        float d2 = __fadd_rn(__fmul_rn(dx, dx), __fmul_rn(dy, dy));        \
        if (d2 < dk5sq) {                                                  \
            float ds = __fsqrt_rn(d2);                                     \
            int j = ids_s[P];                                              \
            if (ds < dk[CK - 1] || (ds == dk[CK - 1] && j < ik[CK - 1])) { \
                float dc = ds; int jc = j;                                 \
                _Pragma("unroll")                                          \
                for (int s = 0; s < CK; ++s) {                             \
                    bool sw = (dc < dk[s]) || (dc == dk[s] && jc < ik[s]); \
                    float od = dk[s]; int oi = ik[s];                      \
                    dk[s] = sw ? dc : od; ik[s] = sw ? jc : oi;            \
                    dc = sw ? od : dc;    jc = sw ? oi : jc;               \
                }                                                          \
                if (ik[CK - 1] != 0x7FFFFFFF)                              \
                    dk5sq = __fmul_rn(dk[CK - 1], dk[CK - 1]) * 1.000001f; \
            }                                                              \
        }                                                                  \
    }

    // ---- fast path: 3x3 neighborhood = 3 contiguous sorted ranges
    {
        int yl = cy > 0 ? cy - 1 : 0, yh = cy < 15 ? cy + 1 : 15;
        int xl = cx > 0 ? cx - 1 : 0, xh = cx < 15 ? cx + 1 : 15;
        for (int yy = yl; yy <= yh; ++yy) {
            int p  = st_s[(yy << 4) + xl];
            int pe = st_s[(yy << 4) + xh + 1];
            for (; p < pe; ++p) KNN_CAND(p)
        }
    }
    // certified r=1 stop
    bool done;
    {
        int x0 = cx - 1, x1 = cx + 1, y0 = cy - 1, y1 = cy + 1;
        done = (x0 <= 0 && y0 <= 0 && x1 >= 15 && y1 >= 15);
        float mL = x0 > 0  ? __fsub_rn(xq, (float)x0 * h)       : 1e30f;
        float mR = x1 < 15 ? __fsub_rn((float)(x1 + 1) * h, xq) : 1e30f;
        float mB = y0 > 0  ? __fsub_rn(yq, (float)y0 * h)       : 1e30f;
        float mT = y1 < 15 ? __fsub_rn((float)(y1 + 1) * h, yq) : 1e30f;
        float bound = fminf(fminf(mL, mR), fminf(mB, mT)) * 0.999999f;
        done = done || (ik[CK - 1] != 0x7FFFFFFF && dk[CK - 1] < bound);
    }
    // ---- rare fallback: general ring expansion from r=2
    if (!done) {
        for (int r = 2; r < 16; ++r) {
            int x0 = cx - r, x1 = cx + r, y0 = cy - r, y1 = cy + r;
            int yl = y0 < 0 ? 0 : y0, yh = y1 > 15 ? 15 : y1;
            int xl = x0 < 0 ? 0 : x0, xh = x1 > 15 ? 15 : x1;
            for (int yy = yl; yy <= yh; ++yy) {
                bool ey = (yy == y0) || (yy == y1);
                if (ey) {
                    int p  = st_s[(yy << 4) + xl];
                    int pe = st_s[(yy << 4) + xh + 1];
                    for (; p < pe; ++p) KNN_CAND(p)
                } else {
                    if (x0 >= 0) {
                        int p  = st_s[(yy << 4) + x0];
                        int pe = st_s[(yy << 4) + x0 + 1];
                        for (; p < pe; ++p) KNN_CAND(p)
                    }
                    if (x1 <= 15) {
                        int p  = st_s[(yy << 4) + x1];
                        int pe = st_s[(yy << 4) + x1 + 1];
                        for (; p < pe; ++p) KNN_CAND(p)
                    }
                }
            }
            if (x0 <= 0 && y0 <= 0 && x1 >= 15 && y1 >= 15) break;
            float mL = x0 > 0  ? __fsub_rn(xq, (float)x0 * h)       : 1e30f;
            float mR = x1 < 15 ? __fsub_rn((float)(x1 + 1) * h, xq) : 1e30f;
            float mB = y0 > 0  ? __fsub_rn(yq, (float)y0 * h)       : 1e30f;
            float mT = y1 < 15 ? __fsub_rn((float)(y1 + 1) * h, yq) : 1e30f;
            float bound = fminf(fminf(mL, mR), fminf(mB, mT)) * 0.999999f;
            if (ik[CK - 1] != 0x7FFFFFFF && dk[CK - 1] < bound) break;
        }
    }
#undef KNN_CAND
    unsigned short* o = nbrs + (unsigned)(b * CN + q) * CK;
#pragma unroll
    for (int s = 0; s < CK; ++s) o[s] = (unsigned short)ik[s];
}

// ---------------------------------------------------------------------------
// k_gemm: per block = 128 rows of one batch (512 blocks). Per-wave 32 rows,
// acc[2][8]. K=768 in 24 chunks of 32, fully unrolled, neighbor indices in
// registers. Fused F3 + bias + leaky epilogue; per-block column partials.
// ---------------------------------------------------------------------------
__global__ void __launch_bounds__(256) k_gemm(
    const float* __restrict__ loc,
    const float* __restrict__ dl,
    const unsigned short* __restrict__ F2b,   // [1024][128] bf16
    const unsigned short* __restrict__ Wnbb,  // [128][768] bf16
    const unsigned short* __restrict__ nbrs,  // [65536][6] u16
    const float* __restrict__ bnb,
    const float* __restrict__ W3d,
    const float* __restrict__ b3d,
    float* __restrict__ outh,          // [64][1025][128]
    float* __restrict__ partials)      // [512][128]
{
    __shared__ unsigned short As[128 * 40];  // 10 KB (stride-40 pad)
    __shared__ unsigned short Bs[128 * 40];  // 10 KB
    __shared__ float psum[4][CD];            // 2 KB

    int t = threadIdx.x;
    int rowbase = blockIdx.x * 128;
    int bb = rowbase >> 10;

    int ar0 = t >> 2, aseg = t & 3;
    int nb0[CK], nb1[CK];
#pragma unroll
    for (int s = 0; s < CK; ++s) {
        nb0[s] = (int)nbrs[(rowbase + ar0) * CK + s];
        nb1[s] = (int)nbrs[(rowbase + ar0 + 64) * CK + s];
    }

    int wave = t >> 6, lane = t & 63;
    int koff = (lane >> 4) * 8;
    int mrow = lane & 15;
    int bd = t >> 1, bhalf = t & 1;

    floatx4 acc[2][8];
#pragma unroll
    for (int i = 0; i < 2; ++i)
#pragma unroll
        for (int j = 0; j < 8; ++j) acc[i][j] = (floatx4){0.f, 0.f, 0.f, 0.f};

#pragma unroll
    for (int c = 0; c < 24; ++c) {
        const int kk = c >> 2;
        const int inner = (c & 3) * 32;
        __syncthreads();
        *(uint4*)&As[ar0 * 40 + aseg * 8] =
            *(const uint4*)(F2b + nb0[kk] * 128 + inner + aseg * 8);
        *(uint4*)&As[(ar0 + 64) * 40 + aseg * 8] =
            *(const uint4*)(F2b + nb1[kk] * 128 + inner + aseg * 8);
        {
            const uint4* src = (const uint4*)(Wnbb + bd * 768 + c * 32 + bhalf * 16);
            *(uint4*)&Bs[bd * 40 + bhalf * 16] = src[0];
            *(uint4*)&Bs[bd * 40 + bhalf * 16 + 8] = src[1];
        }
        __syncthreads();
        short8 af[2];
#pragma unroll
        for (int i = 0; i < 2; ++i)
            af[i] = *(const short8*)&As[(wave * 32 + i * 16 + mrow) * 40 + koff];
#pragma unroll
        for (int j = 0; j < 8; ++j) {
            short8 bfr = *(const short8*)&Bs[(j * 16 + mrow) * 40 + koff];
#pragma unroll
            for (int i = 0; i < 2; ++i)
                acc[i][j] = __builtin_amdgcn_mfma_f32_16x16x32_bf16(
                    af[i], bfr, acc[i][j], 0, 0, 0);
        }
    }

    // Epilogue. C/D: col = lane&15, row = (lane>>4)*4 + reg.
    int lq = lane >> 4, lc = lane & 15;
    float rl0[8], rl1[8], rdl[8]; int rn[8];
#pragma unroll
    for (int ir = 0; ir < 8; ++ir) {
        int i = ir >> 2, r = ir & 3;
        int mg = rowbase + wave * 32 + i * 16 + lq * 4 + r;
        float2 l2 = ((const float2*)loc)[mg];
        rl0[ir] = l2.x; rl1[ir] = l2.y; rdl[ir] = dl[mg];
        rn[ir] = mg & 1023;
    }
#pragma unroll
    for (int j = 0; j < 8; ++j) {
        int d = j * 16 + lc;
        float w0 = W3d[d * 3], w1 = W3d[d * 3 + 1], w2 = W3d[d * 3 + 2];
        float bias = b3d[d] + bnb[d];
        float csum = 0.f;
#pragma unroll
        for (int ir = 0; ir < 8; ++ir) {
            int i = ir >> 2, r = ir & 3;
            float v = acc[i][j][r] + bias + rl0[ir] * w0 + rl1[ir] * w1 + rdl[ir] * w2;
            float lr = v >= 0.f ? v : 0.01f * v;
            outh[((long)bb * 1025 + rn[ir] + 1) * 128 + d] = lr;
            csum += lr;
        }
        csum += __shfl_xor(csum, 16);
        csum += __shfl_xor(csum, 32);
        if (lq == 0) psum[wave][d] = csum;
    }
    __syncthreads();
    if (t < CD)
        partials[blockIdx.x * 128 + t] =
            psum[0][t] + psum[1][t] + psum[2][t] + psum[3][t];
}

// ---------------------------------------------------------------------------
// k_fin: reduce 8 block-partials/batch + depot row + mean/1025.
// ---------------------------------------------------------------------------
__global__ void k_fin(const float* __restrict__ depot,
                      const float* __restrict__ Wdep,
                      const float* __restrict__ bdep,
                      const float* __restrict__ partials,
                      float* __restrict__ out) {
    int idx = blockIdx.x * 256 + threadIdx.x;   // 64*128
    int b = idx >> 7, d = idx & 127;
    float acc = 0.f;
#pragma unroll
    for (int g = 0; g < 8; ++g) acc += partials[(b * 8 + g) * 128 + d];
    float dv = depot[b * 2] * Wdep[d * 2] + depot[b * 2 + 1] * Wdep[d * 2 + 1] + bdep[d];
    float lr = dv >= 0.f ? dv : 0.01f * dv;
    out[(long)b * 1025 * 128 + d] = lr;
    out[(long)CB * 1025 * 128 + idx] = (acc + lr) * (1.0f / 1025.0f);
}

extern "C" void kernel_launch(void* const* d_in, const int* in_sizes, int n_in,
                              void* d_out, int out_size, void* d_ws, size_t ws_size,
                              hipStream_t stream) {
    const float* loc      = (const float*)d_in[0];
    const float* deadline = (const float*)d_in[1];
    const float* depot    = (const float*)d_in[2];
    const float* W3d      = (const float*)d_in[3];
    const float* b3d      = (const float*)d_in[4];
    const float* W2d      = (const float*)d_in[5];
    const float* b2d      = (const float*)d_in[6];
    const float* Wnb      = (const float*)d_in[7];
    const float* bnb      = (const float*)d_in[8];
    const float* Wdep     = (const float*)d_in[9];
    const float* bdep     = (const float*)d_in[10];
    float* out = (float*)d_out;

    char* ws = (char*)d_ws;
    unsigned short* F2b   = (unsigned short*)(ws + WS_F2B);
    unsigned short* Wnbb  = (unsigned short*)(ws + WS_WNBB);
    float* partials       = (float*)(ws + WS_PART);
    unsigned short* nbrs  = (unsigned short*)(ws + WS_NBRS);
    unsigned short* ids   = (unsigned short*)(ws + WS_IDS);
    int* starts           = (int*)(ws + WS_STARTS);

    k_grid<<<64, 256, 0, stream>>>(loc, W2d, b2d, Wnb, ids, starts, F2b, Wnbb);
    k_knn<<<256, 256, 0, stream>>>(loc, ids, starts, nbrs);
    k_gemm<<<512, 256, 0, stream>>>(loc, deadline, F2b, Wnbb, nbrs, bnb,
                                    W3d, b3d, out, partials);
    k_fin<<<32, 256, 0, stream>>>(depot, Wdep, bdep, partials, out);
}

// Round 10
// 139.313 us; speedup vs baseline: 2.1354x; 1.0259x over previous
//
#include <hip/hip_runtime.h>
#include <hip/hip_bf16.h>

// Problem constants (B=64, N=1024, D=128, K=6)
#define CB 64
#define CN 1024
#define CD 128
#define CK 6

typedef __attribute__((ext_vector_type(8))) short short8;
typedef __attribute__((ext_vector_type(4))) float floatx4;

__device__ __forceinline__ unsigned short f2bf(float f) {
    union { float f; unsigned u; } c; c.f = f;
    unsigned u = c.u;
    u += 0x7FFFu + ((u >> 16) & 1u);
    return (unsigned short)(u >> 16);
}

// ws layout (bytes) — total ~1.92 MB
#define WS_F2B    0          // [1024][128] bf16 = 256 KB
#define WS_WNBB   262144     // [128][768] bf16  = 192 KB
#define WS_PART   458752     // [512][128] f32   = 256 KB (512 KB reserved)
#define WS_NBRS   983040     // [65536][6] u16   = 768 KB
#define WS_IDS    1769472    // [64][1024] u16   = 128 KB
#define WS_STARTS 1900544    // [64][257] i32    = 64.25 KB

// ---------------------------------------------------------------------------
// k_grid: one block per batch. (a) counting-sort points into 16x16 cells,
// (b) fused precompute of F2b (batch-0 F2, bf16) and Wnbb (bf16) slices.
// ---------------------------------------------------------------------------
__global__ void __launch_bounds__(256) k_grid(
    const float* __restrict__ loc,
    const float* __restrict__ W2d,
    const float* __restrict__ b2d,
    const float* __restrict__ Wnb,
    unsigned short* __restrict__ ids,
    int* __restrict__ starts,
    unsigned short* __restrict__ F2b,
    unsigned short* __restrict__ Wnbb)
{
    __shared__ float2 pts[CN];
    __shared__ int cnt[256];
    __shared__ int base[256];
    int b = blockIdx.x, t = threadIdx.x;
    const float2* lb = (const float2*)loc + b * CN;
#pragma unroll
    for (int r = 0; r < 4; ++r) pts[t + r * 256] = lb[t + r * 256];
    cnt[t] = 0;
    __syncthreads();
    int mycell[4];
#pragma unroll
    for (int r = 0; r < 4; ++r) {
        float2 p = pts[t * 4 + r];
        int cx = (int)(p.x * 16.0f); cx = cx > 15 ? 15 : cx;
        int cy = (int)(p.y * 16.0f); cy = cy > 15 ? 15 : cy;
        mycell[r] = (cy << 4) + cx;
        atomicAdd(&cnt[mycell[r]], 1);
    }
    __syncthreads();
    for (int off = 1; off < 256; off <<= 1) {
        int u = (t >= off) ? cnt[t - off] : 0;
        __syncthreads();
        cnt[t] += u;
        __syncthreads();
    }
    int excl = (t == 0) ? 0 : cnt[t - 1];
    base[t] = excl;
    starts[b * 257 + t] = excl;
    if (t == 255) starts[b * 257 + 256] = cnt[255];
    __syncthreads();
#pragma unroll
    for (int r = 0; r < 4; ++r) {
        int pos = atomicAdd(&base[mycell[r]], 1);
        ids[b * CN + pos] = (unsigned short)(t * 4 + r);
    }
    // fused precompute
#pragma unroll
    for (int e = 0; e < 8; ++e) {
        int idx = b * 2048 + e * 256 + t;
        int n = idx >> 7, d = idx & 127;
        float v = fmaf(loc[n * 2], W2d[d * 2],
                  fmaf(loc[n * 2 + 1], W2d[d * 2 + 1], b2d[d]));
        F2b[idx] = f2bf(v);
    }
#pragma unroll
    for (int e = 0; e < 6; ++e) {
        int idx = b * 1536 + e * 256 + t;
        Wnbb[idx] = f2bf(Wnb[idx]);
    }
}

// ---------------------------------------------------------------------------
// k_knn: 1024 blocks x 256 threads, FOUR threads per query (64 queries/block,
// at sorted positions -> cell-coherent waves, 16 waves/CU). Thread pi=t&3
// scans candidate positions p = range_start+pi step 4 (disjoint partitions,
// each exact top-6 via lexicographic (ds,idx) insertion), then 2 shuffle-xor
// merge rounds produce the exact global top-6. Per-thread certified ring stop
// is conservative-safe (unscanned dist >= bound > own dk[5] => can't reach
// global top-6 past 6 better candidates). Bit-exact d2/sqrt vs numpy.
// ---------------------------------------------------------------------------
__global__ void __launch_bounds__(256) k_knn(
    const float* __restrict__ loc,
    const unsigned short* __restrict__ ids,
    const int* __restrict__ starts,
    unsigned short* __restrict__ nbrs)
{
    __shared__ float2 xy_tmp[CN];            // original order
    __shared__ float2 xy_s[CN];              // sorted order
    __shared__ unsigned short ids_s[CN];
    __shared__ int st_s[257];
    int t = threadIdx.x;
    int b = blockIdx.x >> 4;                 // 16 blocks per batch
    int qbase = (blockIdx.x & 15) << 6;      // 64 queries per block
    const float2* lb = (const float2*)loc + b * CN;
#pragma unroll
    for (int r = 0; r < 4; ++r) {
        int p = t + r * 256;
        xy_tmp[p] = lb[p];
        ids_s[p] = ids[b * CN + p];
    }
    st_s[t] = starts[b * 257 + t];
    if (t == 0) st_s[256] = starts[b * 257 + 256];
    __syncthreads();
#pragma unroll
    for (int r = 0; r < 4; ++r) {
        int p = t + r * 256;
        xy_s[p] = xy_tmp[ids_s[p]];
    }
    __syncthreads();

    int qp = qbase + (t >> 2);               // sorted position of my query
    int pi = t & 3;                          // partition offset
    int q = ids_s[qp];
    float2 qxy = xy_s[qp];
    float xq = qxy.x, yq = qxy.y;
    int cx = (int)(xq * 16.0f); cx = cx > 15 ? 15 : cx;
    int cy = (int)(yq * 16.0f); cy = cy > 15 ? 15 : cy;
    float dk[CK]; int ik[CK];
#pragma unroll
    for (int s = 0; s < CK; ++s) { dk[s] = 1e30f; ik[s] = 0x7FFFFFFF; }
    float dk5sq = __builtin_inff();
    const float h = 0.0625f;

#define KNN_CAND(P)                                                        \
    {                                                                      \
        float2 v = xy_s[P];                                                \
        float dx = __fsub_rn(v.x, xq);                                     \
        float dy = __fsub_rn(v.y, yq);                                     \
        float d2 = __fadd_rn(__fmul_rn(dx, dx), __fmul_rn(dy, dy));        \
        if (d2 < dk5sq) {                                                  \
            float ds = __fsqrt_rn(d2);                                     \
            int j = ids_s[P];                                              \
            if (ds < dk[CK - 1] || (ds == dk[CK - 1] && j < ik[CK - 1])) { \
                float dc = ds; int jc = j;                                 \
                _Pragma("unroll")                                          \
                for (int s = 0; s < CK; ++s) {                             \
                    bool sw = (dc < dk[s]) || (dc == dk[s] && jc < ik[s]); \
                    float od = dk[s]; int oi = ik[s];                      \
                    dk[s] = sw ? dc : od; ik[s] = sw ? jc : oi;            \
                    dc = sw ? od : dc;    jc = sw ? oi : jc;               \
                }                                                          \
                if (ik[CK - 1] != 0x7FFFFFFF)                              \
                    dk5sq = __fmul_rn(dk[CK - 1], dk[CK - 1]) * 1.000001f; \
            }                                                              \
        }                                                                  \
    }

    // ---- fast path: 3x3 neighborhood = 3 contiguous sorted ranges
    {
        int yl = cy > 0 ? cy - 1 : 0, yh = cy < 15 ? cy + 1 : 15;
        int xl = cx > 0 ? cx - 1 : 0, xh = cx < 15 ? cx + 1 : 15;
        for (int yy = yl; yy <= yh; ++yy) {
            int p  = st_s[(yy << 4) + xl] + pi;
            int pe = st_s[(yy << 4) + xh + 1];
            for (; p < pe; p += 4) KNN_CAND(p)
        }
    }
    // certified r=1 stop (per-thread, conservative)
    bool done;
    {
        int x0 = cx - 1, x1 = cx + 1, y0 = cy - 1, y1 = cy + 1;
        done = (x0 <= 0 && y0 <= 0 && x1 >= 15 && y1 >= 15);
        float mL = x0 > 0  ? __fsub_rn(xq, (float)x0 * h)       : 1e30f;
        float mR = x1 < 15 ? __fsub_rn((float)(x1 + 1) * h, xq) : 1e30f;
        float mB = y0 > 0  ? __fsub_rn(yq, (float)y0 * h)       : 1e30f;
        float mT = y1 < 15 ? __fsub_rn((float)(y1 + 1) * h, yq) : 1e30f;
        float bound = fminf(fminf(mL, mR), fminf(mB, mT)) * 0.999999f;
        done = done || (ik[CK - 1] != 0x7FFFFFFF && dk[CK - 1] < bound);
    }
    // ---- rare fallback: general ring expansion from r=2 (same partition)
    if (!done) {
        for (int r = 2; r < 16; ++r) {
            int x0 = cx - r, x1 = cx + r, y0 = cy - r, y1 = cy + r;
            int yl = y0 < 0 ? 0 : y0, yh = y1 > 15 ? 15 : y1;
            int xl = x0 < 0 ? 0 : x0, xh = x1 > 15 ? 15 : x1;
            for (int yy = yl; yy <= yh; ++yy) {
                bool ey = (yy == y0) || (yy == y1);
                if (ey) {
                    int p  = st_s[(yy << 4) + xl] + pi;
                    int pe = st_s[(yy << 4) + xh + 1];
                    for (; p < pe; p += 4) KNN_CAND(p)
                } else {
                    if (x0 >= 0) {
                        int p  = st_s[(yy << 4) + x0] + pi;
                        int pe = st_s[(yy << 4) + x0 + 1];
                        for (; p < pe; p += 4) KNN_CAND(p)
                    }
                    if (x1 <= 15) {
                        int p  = st_s[(yy << 4) + x1] + pi;
                        int pe = st_s[(yy << 4) + x1 + 1];
                        for (; p < pe; p += 4) KNN_CAND(p)
                    }
                }
            }
            if (x0 <= 0 && y0 <= 0 && x1 >= 15 && y1 >= 15) break;
            float mL = x0 > 0  ? __fsub_rn(xq, (float)x0 * h)       : 1e30f;
            float mR = x1 < 15 ? __fsub_rn((float)(x1 + 1) * h, xq) : 1e30f;
            float mB = y0 > 0  ? __fsub_rn(yq, (float)y0 * h)       : 1e30f;
            float mT = y1 < 15 ? __fsub_rn((float)(y1 + 1) * h, yq) : 1e30f;
            float bound = fminf(fminf(mL, mR), fminf(mB, mT)) * 0.999999f;
            if (ik[CK - 1] != 0x7FFFFFFF && dk[CK - 1] < bound) break;
        }
    }
#undef KNN_CAND

    // ---- merge the 4 disjoint partition lists (all sorted lexicographic).
    // Insert partner's entries with the same constant-indexed chain.
#define KNN_MERGE(MASK)                                                     \
    {                                                                       \
        float od[CK]; int oi[CK];                                           \
        _Pragma("unroll")                                                   \
        for (int s = 0; s < CK; ++s) {                                      \
            od[s] = __shfl_xor(dk[s], MASK);                                \
            oi[s] = __shfl_xor(ik[s], MASK);                                \
        }                                                                   \
        _Pragma("unroll")                                                   \
        for (int e = 0; e < CK; ++e) {                                      \
            float dc = od[e]; int jc = oi[e];                               \
            if ((dc < dk[CK - 1]) || (dc == dk[CK - 1] && jc < ik[CK - 1])) { \
                _Pragma("unroll")                                           \
                for (int s = 0; s < CK; ++s) {                              \
                    bool sw = (dc < dk[s]) || (dc == dk[s] && jc < ik[s]);  \
                    float td = dk[s]; int ti = ik[s];                       \
                    dk[s] = sw ? dc : td; ik[s] = sw ? jc : ti;             \
                    dc = sw ? td : dc;    jc = sw ? ti : jc;                \
                }                                                           \
            }                                                               \
        }                                                                   \
    }
    KNN_MERGE(1)
    KNN_MERGE(2)
#undef KNN_MERGE

    if (pi == 0) {
        unsigned short* o = nbrs + (unsigned)(b * CN + q) * CK;
#pragma unroll
        for (int s = 0; s < CK; ++s) o[s] = (unsigned short)ik[s];
    }
}

// ---------------------------------------------------------------------------
// k_gemm: per block = 128 rows of one batch (512 blocks). Per-wave 32 rows,
// acc[2][8]. K=768 in 24 chunks of 32, fully unrolled, neighbor indices in
// registers. Fused F3 + bias + leaky epilogue; per-block column partials.
// ---------------------------------------------------------------------------
__global__ void __launch_bounds__(256) k_gemm(
    const float* __restrict__ loc,
    const float* __restrict__ dl,
    const unsigned short* __restrict__ F2b,   // [1024][128] bf16
    const unsigned short* __restrict__ Wnbb,  // [128][768] bf16
    const unsigned short* __restrict__ nbrs,  // [65536][6] u16
    const float* __restrict__ bnb,
    const float* __restrict__ W3d,
    const float* __restrict__ b3d,
    float* __restrict__ outh,          // [64][1025][128]
    float* __restrict__ partials)      // [512][128]
{
    __shared__ unsigned short As[128 * 40];  // 10 KB (stride-40 pad)
    __shared__ unsigned short Bs[128 * 40];  // 10 KB
    __shared__ float psum[4][CD];            // 2 KB

    int t = threadIdx.x;
    int rowbase = blockIdx.x * 128;
    int bb = rowbase >> 10;

    int ar0 = t >> 2, aseg = t & 3;
    int nb0[CK], nb1[CK];
#pragma unroll
    for (int s = 0; s < CK; ++s) {
        nb0[s] = (int)nbrs[(rowbase + ar0) * CK + s];
        nb1[s] = (int)nbrs[(rowbase + ar0 + 64) * CK + s];
    }

    int wave = t >> 6, lane = t & 63;
    int koff = (lane >> 4) * 8;
    int mrow = lane & 15;
    int bd = t >> 1, bhalf = t & 1;

    floatx4 acc[2][8];
#pragma unroll
    for (int i = 0; i < 2; ++i)
#pragma unroll
        for (int j = 0; j < 8; ++j) acc[i][j] = (floatx4){0.f, 0.f, 0.f, 0.f};

#pragma unroll
    for (int c = 0; c < 24; ++c) {
        const int kk = c >> 2;
        const int inner = (c & 3) * 32;
        __syncthreads();
        *(uint4*)&As[ar0 * 40 + aseg * 8] =
            *(const uint4*)(F2b + nb0[kk] * 128 + inner + aseg * 8);
        *(uint4*)&As[(ar0 + 64) * 40 + aseg * 8] =
            *(const uint4*)(F2b + nb1[kk] * 128 + inner + aseg * 8);
        {
            const uint4* src = (const uint4*)(Wnbb + bd * 768 + c * 32 + bhalf * 16);
            *(uint4*)&Bs[bd * 40 + bhalf * 16] = src[0];
            *(uint4*)&Bs[bd * 40 + bhalf * 16 + 8] = src[1];
        }
        __syncthreads();
        short8 af[2];
#pragma unroll
        for (int i = 0; i < 2; ++i)
            af[i] = *(const short8*)&As[(wave * 32 + i * 16 + mrow) * 40 + koff];
#pragma unroll
        for (int j = 0; j < 8; ++j) {
            short8 bfr = *(const short8*)&Bs[(j * 16 + mrow) * 40 + koff];
#pragma unroll
            for (int i = 0; i < 2; ++i)
                acc[i][j] = __builtin_amdgcn_mfma_f32_16x16x32_bf16(
                    af[i], bfr, acc[i][j], 0, 0, 0);
        }
    }

    // Epilogue. C/D: col = lane&15, row = (lane>>4)*4 + reg.
    int lq = lane >> 4, lc = lane & 15;
    float rl0[8], rl1[8], rdl[8]; int rn[8];
#pragma unroll
    for (int ir = 0; ir < 8; ++ir) {
        int i = ir >> 2, r = ir & 3;
        int mg = rowbase + wave * 32 + i * 16 + lq * 4 + r;
        float2 l2 = ((const float2*)loc)[mg];
        rl0[ir] = l2.x; rl1[ir] = l2.y; rdl[ir] = dl[mg];
        rn[ir] = mg & 1023;
    }
#pragma unroll
    for (int j = 0; j < 8; ++j) {
        int d = j * 16 + lc;
        float w0 = W3d[d * 3], w1 = W3d[d * 3 + 1], w2 = W3d[d * 3 + 2];
        float bias = b3d[d] + bnb[d];
        float csum = 0.f;
#pragma unroll
        for (int ir = 0; ir < 8; ++ir) {
            int i = ir >> 2, r = ir & 3;
            float v = acc[i][j][r] + bias + rl0[ir] * w0 + rl1[ir] * w1 + rdl[ir] * w2;
            float lr = v >= 0.f ? v : 0.01f * v;
            outh[((long)bb * 1025 + rn[ir] + 1) * 128 + d] = lr;
            csum += lr;
        }
        csum += __shfl_xor(csum, 16);
        csum += __shfl_xor(csum, 32);
        if (lq == 0) psum[wave][d] = csum;
    }
    __syncthreads();
    if (t < CD)
        partials[blockIdx.x * 128 + t] =
            psum[0][t] + psum[1][t] + psum[2][t] + psum[3][t];
}

// ---------------------------------------------------------------------------
// k_fin: reduce 8 block-partials/batch + depot row + mean/1025.
// ---------------------------------------------------------------------------
__global__ void k_fin(const float* __restrict__ depot,
                      const float* __restrict__ Wdep,
                      const float* __restrict__ bdep,
                      const float* __restrict__ partials,
                      float* __restrict__ out) {
    int idx = blockIdx.x * 256 + threadIdx.x;   // 64*128
    int b = idx >> 7, d = idx & 127;
    float acc = 0.f;
#pragma unroll
    for (int g = 0; g < 8; ++g) acc += partials[(b * 8 + g) * 128 + d];
    float dv = depot[b * 2] * Wdep[d * 2] + depot[b * 2 + 1] * Wdep[d * 2 + 1] + bdep[d];
    float lr = dv >= 0.f ? dv : 0.01f * dv;
    out[(long)b * 1025 * 128 + d] = lr;
    out[(long)CB * 1025 * 128 + idx] = (acc + lr) * (1.0f / 1025.0f);
}

extern "C" void kernel_launch(void* const* d_in, const int* in_sizes, int n_in,
                              void* d_out, int out_size, void* d_ws, size_t ws_size,
                              hipStream_t stream) {
    const float* loc      = (const float*)d_in[0];
    const float* deadline = (const float*)d_in[1];
    const float* depot    = (const float*)d_in[2];
    const float* W3d      = (const float*)d_in[3];
    const float* b3d      = (const float*)d_in[4];
    const float* W2d      = (const float*)d_in[5];
    const float* b2d      = (const float*)d_in[6];
    const float* Wnb      = (const float*)d_in[7];
    const float* bnb      = (const float*)d_in[8];
    const float* Wdep     = (const float*)d_in[9];
    const float* bdep     = (const float*)d_in[10];
    float* out = (float*)d_out;

    char* ws = (char*)d_ws;
    unsigned short* F2b   = (unsigned short*)(ws + WS_F2B);
    unsigned short* Wnbb  = (unsigned short*)(ws + WS_WNBB);
    float* partials       = (float*)(ws + WS_PART);
    unsigned short* nbrs  = (unsigned short*)(ws + WS_NBRS);
    unsigned short* ids   = (unsigned short*)(ws + WS_IDS);
    int* starts           = (int*)(ws + WS_STARTS);

    k_grid<<<64, 256, 0, stream>>>(loc, W2d, b2d, Wnb, ids, starts, F2b, Wnbb);
    k_knn<<<1024, 256, 0, stream>>>(loc, ids, starts, nbrs);
    k_gemm<<<512, 256, 0, stream>>>(loc, deadline, F2b, Wnbb, nbrs, bnb,
                                    W3d, b3d, out, partials);
    k_fin<<<32, 256, 0, stream>>>(depot, Wdep, bdep, partials, out);
}